// Round 10
// baseline (3417.018 us; speedup 1.0000x reference)
//
#include <hip/hip_runtime.h>
#include <math.h>

// PointNet++ SetAbstraction for MI355X.
// B=4 N=8192 M=2048 K=64 C_IN=64, dims 67->64->64->128, radius 0.2.
// Exactness-critical paths (FPS argmax + bucket pruning, ball-query radius
// test) use __f*_rn intrinsics; pruning relies on IEEE rounding monotonicity
// so skipped work is provably identity. No FMA in exact paths.

constexpr int B = 4, N = 8192, M = 2048, K = 64;
constexpr int C0 = 67;              // 3 + 64 input channels
constexpr int NB_CHAIN = B * M;     // one block per (b,m) = 8192
constexpr int NROW = B * M * K;     // 524288 rows through the MLP

#define DEVFN static __device__ __forceinline__

// DPP-shifted copy: invalid lanes get 0 (neutral for max of values >= 0).
template <int CTRL>
DEVFN float dpp_shift0(float x) {
  return __uint_as_float((unsigned)__builtin_amdgcn_update_dpp(
      0, (int)__float_as_uint(x), CTRL, 0xf, 0xf, true));
}
template <int CTRL>
DEVFN unsigned dpp_shift0u(unsigned x) {
  return (unsigned)__builtin_amdgcn_update_dpp(0, (int)x, CTRL, 0xf, 0xf, true);
}
DEVFN float wave_max_f32(float x) {   // broadcast wave max (values >= -1)
  x = fmaxf(x, dpp_shift0<0x111>(x));
  x = fmaxf(x, dpp_shift0<0x112>(x));
  x = fmaxf(x, dpp_shift0<0x114>(x));
  x = fmaxf(x, dpp_shift0<0x118>(x));
  x = fmaxf(x, dpp_shift0<0x142>(x));
  x = fmaxf(x, dpp_shift0<0x143>(x));
  return __shfl(x, 63);
}
DEVFN unsigned wave_max_u32(unsigned x) {
  unsigned t;
  t = dpp_shift0u<0x111>(x); x = x > t ? x : t;
  t = dpp_shift0u<0x112>(x); x = x > t ? x : t;
  t = dpp_shift0u<0x114>(x); x = x > t ? x : t;
  t = dpp_shift0u<0x118>(x); x = x > t ? x : t;
  t = dpp_shift0u<0x142>(x); x = x > t ? x : t;
  t = dpp_shift0u<0x143>(x); x = x > t ? x : t;
  return (unsigned)__shfl((int)x, 63);
}

// ---------------------------------------------------------------- transpose
__global__ __launch_bounds__(256) void transpose_kernel(
    const float* __restrict__ P, const float* __restrict__ F,
    float4* __restrict__ pts4, float* __restrict__ ft)
{
  int g = blockIdx.x * 256 + threadIdx.x;        // 0 .. B*N-1
  int b = g >> 13, i = g & (N - 1);
  const float* Pb = P + (size_t)b * 3 * N;
  pts4[g] = make_float4(Pb[i], Pb[N + i], Pb[2 * N + i], 0.f);
  const float* Fb = F + (size_t)b * 64 * N;
  float* o = ft + (size_t)g * 64;
  #pragma unroll 8
  for (int c = 0; c < 64; ++c) o[c] = Fb[(size_t)c * N + i];
}

__global__ __launch_bounds__(256) void prep_weights(
    const float* __restrict__ W0, const float* __restrict__ W1,
    const float* __restrict__ W2,
    float* __restrict__ w0T, float* __restrict__ w1T, float* __restrict__ w2T)
{
  int t = threadIdx.x;
  for (int x = t; x < 67 * 64; x += 256) { int k = x >> 6, o = x & 63;  w0T[x] = W0[o * 67 + k]; }
  for (int x = t; x < 64 * 64; x += 256) { int k = x >> 6, o = x & 63;  w1T[x] = W1[o * 64 + k]; }
  for (int x = t; x < 64 * 128; x += 256){ int k = x >> 7, o = x & 127; w2T[x] = W2[o * 64 + k]; }
}

// ---------------------------------------------------------------- FPS
// Bucket-pruned exact FPS. One block per batch, 512 threads.
// Points counting-sorted into 128 spatial cells (4x4x8 over [0,1)^3) in LDS.
// Per bucket: bbox + key = max over members of (mind_bits<<32 | ~orig_idx).
// Per step: bucket skipped iff dlow(bbox,c) >= ub. dlow uses the same
// __f*_rn ops as the member distance; IEEE rounding is monotone, so
// computed d >= dlow for every member => fminf(mind,d)==mind: skipping is
// bit-exact. u64 key max = (max mind, min orig idx) = jnp.argmax tie rule.
constexpr int FPS_T = 512;

__global__ __launch_bounds__(512) void fps_kernel(
    const float* __restrict__ P, float4* __restrict__ q4, float* __restrict__ out_q)
{
  __shared__ float sx[N], sy[N], sz[N];          // sorted coords   96 KB
  __shared__ float smind[N];                     // sorted minds    32 KB
  __shared__ unsigned short ssidx[N];            // orig idx        16 KB
  __shared__ float bb[6][128];                   // xlo,xhi,ylo,yhi,zlo,zhi
  __shared__ unsigned long long bkey[128];
  __shared__ unsigned short bspos[128];          // sorted pos of bucket argmax
  __shared__ int starts[129];
  __shared__ int hist[128];
  __shared__ unsigned short act[2][64];
  __shared__ int nact[2];
  __shared__ unsigned short swidx[M];            // selected sorted positions
  __shared__ float cc[3];
  __shared__ int spos0;

  const int b = blockIdx.x, tid = threadIdx.x;
  const int wv = tid >> 6, lane = tid & 63;
  const float* Pb = P + (size_t)b * 3 * N;

  // ---- load + cell ids + histogram
  float lx[16], ly[16], lz[16]; int lcid[16];
  if (tid < 128) hist[tid] = 0;
  __syncthreads();
  #pragma unroll
  for (int j = 0; j < 16; ++j) {
    int i = tid + j * FPS_T;
    lx[j] = Pb[i]; ly[j] = Pb[N + i]; lz[j] = Pb[2 * N + i];
    int cxi = min((int)(lx[j] * 4.f), 3);
    int cyi = min((int)(ly[j] * 4.f), 3);
    int czi = min((int)(lz[j] * 8.f), 7);
    lcid[j] = (cxi << 5) | (cyi << 3) | czi;
    atomicAdd(&hist[lcid[j]], 1);
  }
  __syncthreads();
  if (tid == 0) {                                 // exclusive prefix
    int acc = 0;
    for (int k = 0; k < 128; ++k) { starts[k] = acc; acc += hist[k]; }
    starts[128] = acc;
  }
  __syncthreads();
  if (tid < 128) hist[tid] = starts[tid];         // reuse as cursor
  __syncthreads();
  #pragma unroll
  for (int j = 0; j < 16; ++j) {                  // scatter
    int i = tid + j * FPS_T;
    int pos = atomicAdd(&hist[lcid[j]], 1);
    sx[pos] = lx[j]; sy[pos] = ly[j]; sz[pos] = lz[j];
    ssidx[pos] = (unsigned short)i;
    smind[pos] = 1e10f;
    if (i == 0) spos0 = pos;
  }
  __syncthreads();
  // ---- bboxes + initial keys (mind=1e10, min orig idx per bucket)
  if (tid < 128) {
    int s0 = starts[tid], s1 = starts[tid + 1];
    float xlo = 1e30f, xhi = -1e30f, ylo = 1e30f, yhi = -1e30f, zlo = 1e30f, zhi = -1e30f;
    unsigned mor = 0; unsigned short msp = 0;
    for (int p = s0; p < s1; ++p) {
      float x = sx[p], y = sy[p], z = sz[p];
      xlo = fminf(xlo, x); xhi = fmaxf(xhi, x);
      ylo = fminf(ylo, y); yhi = fmaxf(yhi, y);
      zlo = fminf(zlo, z); zhi = fmaxf(zhi, z);
      unsigned no = ~(unsigned)ssidx[p];
      if (no > mor) { mor = no; msp = (unsigned short)p; }
    }
    bb[0][tid] = xlo; bb[1][tid] = xhi; bb[2][tid] = ylo;
    bb[3][tid] = yhi; bb[4][tid] = zlo; bb[5][tid] = zhi;
    bkey[tid] = (s1 > s0)
        ? (((unsigned long long)__float_as_uint(1e10f) << 32) | mor) : 0ull;
    bspos[tid] = msp;
  }
  if (tid == 0) swidx[0] = (unsigned short)spos0;
  __syncthreads();
  float cx = sx[spos0], cy = sy[spos0], cz = sz[spos0];

  for (int s = 1; s < M; ++s) {
    // --- phase 1: bucket check (waves 0,1), build active lists
    if (tid < 128) {
      float ax = fmaxf(0.f, fmaxf(__fsub_rn(bb[0][tid], cx), __fsub_rn(cx, bb[1][tid])));
      float ay = fmaxf(0.f, fmaxf(__fsub_rn(bb[2][tid], cy), __fsub_rn(cy, bb[3][tid])));
      float az = fmaxf(0.f, fmaxf(__fsub_rn(bb[4][tid], cz), __fsub_rn(cz, bb[5][tid])));
      float dlow = __fadd_rn(__fadd_rn(__fmul_rn(ax, ax), __fmul_rn(ay, ay)), __fmul_rn(az, az));
      float ub = __uint_as_float((unsigned)(bkey[tid] >> 32));
      bool actv = dlow < ub;                       // skip iff dlow >= ub
      unsigned long long am = __ballot(actv);
      int pos = (int)__popcll(am & ((1ull << lane) - 1ull));
      if (actv) act[wv][pos] = (unsigned short)tid;
      if (lane == 0) nact[wv] = (int)__popcll(am);
    }
    __syncthreads();                               // A
    const int n0 = nact[0], ntot = n0 + nact[1];
    // --- phase 2: process active buckets, waves round-robin
    for (int a = wv; a < ntot; a += 8) {
      int k = (a < n0) ? act[0][a] : act[1][a - n0];
      int s0 = starts[k], s1 = starts[k + 1];
      unsigned long long bestk = 0ull, myrec = 0ull;
      int cp = 0;
      for (int off = s0; off < s1; off += 64) {
        int p = off + lane;
        float nm = -1.f; unsigned mor = 0u;
        if (p < s1) {
          float dx = __fsub_rn(sx[p], cx), dy = __fsub_rn(sy[p], cy), dz = __fsub_rn(sz[p], cz);
          float d = __fadd_rn(__fadd_rn(__fmul_rn(dx, dx), __fmul_rn(dy, dy)), __fmul_rn(dz, dz));
          nm = fminf(smind[p], d);
          smind[p] = nm;
          mor = ~(unsigned)ssidx[p];
        }
        float wvmax = wave_max_f32(nm);
        unsigned cand = (nm == wvmax) ? mor : 0u;
        unsigned wor = wave_max_u32(cand);
        unsigned long long kk =
            ((unsigned long long)__float_as_uint(wvmax) << 32) | wor;
        if (nm == wvmax && mor == wor && kk > myrec) { myrec = kk; cp = p; }
        if (kk > bestk) bestk = kk;
      }
      if (myrec == bestk && bestk != 0ull) {       // unique owner lane
        bkey[k] = bestk;
        bspos[k] = (unsigned short)cp;
      }
    }
    __syncthreads();                               // B
    // --- phase 3: global reduce over 128 bucket keys (wave 0 only)
    if (wv == 0) {
      unsigned long long k1 = bkey[lane], k2 = bkey[lane + 64];
      unsigned long long kk = k1 > k2 ? k1 : k2;
      float vh = __uint_as_float((unsigned)(kk >> 32));
      float vmax = wave_max_f32(vh);
      unsigned cand = (vh == vmax) ? (unsigned)(kk & 0xFFFFFFFFull) : 0u;
      unsigned lomax = wave_max_u32(cand);
      unsigned long long fin =
          ((unsigned long long)__float_as_uint(vmax) << 32) | lomax;
      int kwin = -1;
      if (k1 == fin) kwin = lane;
      if (k2 == fin) kwin = lane + 64;
      if (kwin >= 0) {                             // unique (keys unique)
        int sp = bspos[kwin];
        cc[0] = sx[sp]; cc[1] = sy[sp]; cc[2] = sz[sp];
        swidx[s] = (unsigned short)sp;
      }
    }
    __syncthreads();                               // D
    cx = cc[0]; cy = cc[1]; cz = cc[2];
  }
  // ---- bulk write-out of the selected centroids
  for (int s2 = tid; s2 < M; s2 += FPS_T) {
    int sp = swidx[s2];
    float xx = sx[sp], yy = sy[sp], zz = sz[sp];
    q4[b * M + s2] = make_float4(xx, yy, zz, 0.f);
    out_q[b * 3 * M + s2]         = xx;
    out_q[b * 3 * M + M + s2]     = yy;
    out_q[b * 3 * M + 2 * M + s2] = zz;
  }
}

// ---------------------------------------------------------------- ball query
// One wave per centroid: first K in-radius indices ascending; pad with first.
__global__ __launch_bounds__(256) void ballquery_kernel(
    const float4* __restrict__ pts4, const float4* __restrict__ q4, int* __restrict__ nbr)
{
  __shared__ int slot[4][K];
  const int wv = threadIdx.x >> 6, lane = threadIdx.x & 63;
  const int qid = blockIdx.x * 4 + wv;
  const int b = qid >> 11;
  const float4 qc = q4[qid];
  const float4* pb = pts4 + (size_t)b * N;
  const float r2 = 0.04f;                 // float(0.2**2), strict <
  int count = 0;
  for (int c0 = 0; c0 < N; c0 += 64) {
    float4 p = pb[c0 + lane];
    float dx = __fsub_rn(p.x, qc.x), dy = __fsub_rn(p.y, qc.y), dz = __fsub_rn(p.z, qc.z);
    float d2 = __fadd_rn(__fadd_rn(__fmul_rn(dx, dx), __fmul_rn(dy, dy)), __fmul_rn(dz, dz));
    bool in = d2 < r2;
    unsigned long long mask = __ballot(in);
    int pos = count + (int)__popcll(mask & ((1ull << lane) - 1ull));
    if (in && pos < K) slot[wv][pos] = c0 + lane;
    count += (int)__popcll(mask);
    if (count >= K) break;
  }
  __syncthreads();
  int valid = count < K ? count : K;
  int v = 0;
  if (valid > 0) {
    int first = slot[wv][0];
    v = (lane < valid) ? slot[wv][lane] : first;
  }
  nbr[(size_t)qid * K + lane] = v;
}

// ---------------------------------------------------------------- MLP chain
DEVFN void conv_tile(float acc[8][8], const float (&xt)[C0 + 1][64],
                     const float* __restrict__ wT, int KK, int OC, int choff, int rg)
{
  #pragma unroll
  for (int i = 0; i < 8; ++i)
    #pragma unroll
    for (int j = 0; j < 8; ++j) acc[i][j] = 0.f;
  for (int k = 0; k < KK; ++k) {
    const float4 xa = *(const float4*)&xt[k][rg * 8];
    const float4 xb = *(const float4*)&xt[k][rg * 8 + 4];
    const float4 wa = *(const float4*)(wT + (size_t)k * OC + choff);
    const float4 wb = *(const float4*)(wT + (size_t)k * OC + choff + 4);
    const float xs[8] = {xa.x, xa.y, xa.z, xa.w, xb.x, xb.y, xb.z, xb.w};
    const float wv[8] = {wa.x, wa.y, wa.z, wa.w, wb.x, wb.y, wb.z, wb.w};
    #pragma unroll
    for (int i = 0; i < 8; ++i)
      #pragma unroll
      for (int j = 0; j < 8; ++j) acc[i][j] = fmaf(xs[i], wv[j], acc[i][j]);
  }
}

DEVFN void bn_relu_store(const float acc[8][8], const float* __restrict__ sc,
                         const float* __restrict__ sh, int choff, int rg,
                         float (&xt)[C0 + 1][64])
{
  float4 s0 = *(const float4*)(sc + choff), s1 = *(const float4*)(sc + choff + 4);
  float4 h0 = *(const float4*)(sh + choff), h1 = *(const float4*)(sh + choff + 4);
  const float scv[8] = {s0.x, s0.y, s0.z, s0.w, s1.x, s1.y, s1.z, s1.w};
  const float shv[8] = {h0.x, h0.y, h0.z, h0.w, h1.x, h1.y, h1.z, h1.w};
  __syncthreads();
  #pragma unroll
  for (int j = 0; j < 8; ++j) {
    float4 a, b;
    a.x = fmaxf(fmaf(acc[0][j], scv[j], shv[j]), 0.f);
    a.y = fmaxf(fmaf(acc[1][j], scv[j], shv[j]), 0.f);
    a.z = fmaxf(fmaf(acc[2][j], scv[j], shv[j]), 0.f);
    a.w = fmaxf(fmaf(acc[3][j], scv[j], shv[j]), 0.f);
    b.x = fmaxf(fmaf(acc[4][j], scv[j], shv[j]), 0.f);
    b.y = fmaxf(fmaf(acc[5][j], scv[j], shv[j]), 0.f);
    b.z = fmaxf(fmaf(acc[6][j], scv[j], shv[j]), 0.f);
    b.w = fmaxf(fmaf(acc[7][j], scv[j], shv[j]), 0.f);
    *(float4*)&xt[choff + j][rg * 8]     = a;
    *(float4*)&xt[choff + j][rg * 8 + 4] = b;
  }
  __syncthreads();
}

DEVFN void stats_tile(const float acc[8][8], int chbase, int lane, int qid,
                      float* __restrict__ Psum, float* __restrict__ Psq)
{
  #pragma unroll
  for (int j = 0; j < 8; ++j) {
    float s = 0.f, q = 0.f;
    #pragma unroll
    for (int i = 0; i < 8; ++i) { s += acc[i][j]; q = fmaf(acc[i][j], acc[i][j], q); }
    s += __shfl_xor(s, 8);  q += __shfl_xor(q, 8);
    s += __shfl_xor(s, 16); q += __shfl_xor(q, 16);
    s += __shfl_xor(s, 32); q += __shfl_xor(q, 32);
    if ((lane >> 3) == 0) {
      Psum[(size_t)(chbase + j) * NB_CHAIN + qid] = s;
      Psq [(size_t)(chbase + j) * NB_CHAIN + qid] = q;
    }
  }
}

DEVFN void maxmin_tile(const float acc[8][8], int chbase, int lane, int qid,
                       float* __restrict__ ymax, float* __restrict__ ymin)
{
  #pragma unroll
  for (int j = 0; j < 8; ++j) {
    float mx = acc[0][j], mn = acc[0][j];
    #pragma unroll
    for (int i = 1; i < 8; ++i) { mx = fmaxf(mx, acc[i][j]); mn = fminf(mn, acc[i][j]); }
    mx = fmaxf(mx, __shfl_xor(mx, 8));  mn = fminf(mn, __shfl_xor(mn, 8));
    mx = fmaxf(mx, __shfl_xor(mx, 16)); mn = fminf(mn, __shfl_xor(mn, 16));
    mx = fmaxf(mx, __shfl_xor(mx, 32)); mn = fminf(mn, __shfl_xor(mn, 32));
    if ((lane >> 3) == 0) {
      ymax[(size_t)(chbase + j) * NB_CHAIN + qid] = mx;
      ymin[(size_t)(chbase + j) * NB_CHAIN + qid] = mn;
    }
  }
}

DEVFN void gather_x0(const float4* __restrict__ pts4, const float* __restrict__ ft,
                     const float4* __restrict__ q4, const int* __restrict__ nbr,
                     int qid, int b, int lane, float (&xt)[C0 + 1][64])
{
  const int i = nbr[(size_t)qid * K + lane];
  const float4 qc = q4[qid];
  const float4 p = pts4[(size_t)b * N + i];
  xt[0][lane] = p.x - qc.x;
  xt[1][lane] = p.y - qc.y;
  xt[2][lane] = p.z - qc.z;
  const float4* fr = (const float4*)(ft + (size_t)(b * N + i) * 64);
  #pragma unroll
  for (int c = 0; c < 16; ++c) {
    float4 f = fr[c];
    xt[3 + 4 * c + 0][lane] = f.x;
    xt[3 + 4 * c + 1][lane] = f.y;
    xt[3 + 4 * c + 2][lane] = f.z;
    xt[3 + 4 * c + 3][lane] = f.w;
  }
  __syncthreads();
}

DEVFN void y_store(const float acc[8][8], float* __restrict__ y, int qid, int rg, int cg)
{
  float* base = y + (size_t)qid * 4096 + (size_t)(cg * 8) * 64 + rg * 8;
  #pragma unroll
  for (int j = 0; j < 8; ++j) {
    float4 a = make_float4(acc[0][j], acc[1][j], acc[2][j], acc[3][j]);
    float4 c = make_float4(acc[4][j], acc[5][j], acc[6][j], acc[7][j]);
    *(float4*)(base + (size_t)j * 64)     = a;
    *(float4*)(base + (size_t)j * 64 + 4) = c;
  }
}
DEVFN void y_load(float acc[8][8], const float* __restrict__ y, int qid, int rg, int cg)
{
  const float* base = y + (size_t)qid * 4096 + (size_t)(cg * 8) * 64 + rg * 8;
  #pragma unroll
  for (int j = 0; j < 8; ++j) {
    float4 a = *(const float4*)(base + (size_t)j * 64);
    float4 c = *(const float4*)(base + (size_t)j * 64 + 4);
    acc[0][j] = a.x; acc[1][j] = a.y; acc[2][j] = a.z; acc[3][j] = a.w;
    acc[4][j] = c.x; acc[5][j] = c.y; acc[6][j] = c.z; acc[7][j] = c.w;
  }
}

__global__ __launch_bounds__(64) void chain_p1(
    const float4* __restrict__ pts4, const float* __restrict__ ft,
    const float4* __restrict__ q4, const int* __restrict__ nbr,
    const float* __restrict__ w0T,
    float* __restrict__ Psum, float* __restrict__ Psq, float* __restrict__ y)
{
  __shared__ float xt[C0 + 1][64];
  const int qid = blockIdx.x, b = qid >> 11, lane = threadIdx.x;
  const int rg = lane >> 3, cg = lane & 7;
  gather_x0(pts4, ft, q4, nbr, qid, b, lane, xt);
  float acc[8][8];
  conv_tile(acc, xt, w0T, 67, 64, cg * 8, rg);
  stats_tile(acc, cg * 8, lane, qid, Psum, Psq);
  y_store(acc, y, qid, rg, cg);
}

template <int LAYER>
__global__ __launch_bounds__(64) void chain_p23(
    const float* __restrict__ wT, const float* __restrict__ sc,
    const float* __restrict__ sh,
    float* __restrict__ Psum, float* __restrict__ Psq,
    float* __restrict__ y, float* __restrict__ ymax, float* __restrict__ ymin)
{
  __shared__ float xt[C0 + 1][64];
  const int qid = blockIdx.x, lane = threadIdx.x;
  const int rg = lane >> 3, cg = lane & 7;
  float acc[8][8];
  y_load(acc, y, qid, rg, cg);
  bn_relu_store(acc, sc, sh, cg * 8, rg, xt);
  if (LAYER == 2) {
    conv_tile(acc, xt, wT, 64, 64, cg * 8, rg);
    stats_tile(acc, cg * 8, lane, qid, Psum, Psq);
    y_store(acc, y, qid, rg, cg);
  } else {
    conv_tile(acc, xt, wT, 64, 128, cg * 8, rg);
    stats_tile(acc, cg * 8, lane, qid, Psum, Psq);
    maxmin_tile(acc, cg * 8, lane, qid, ymax, ymin);
    conv_tile(acc, xt, wT, 64, 128, 64 + cg * 8, rg);
    stats_tile(acc, 64 + cg * 8, lane, qid, Psum, Psq);
    maxmin_tile(acc, 64 + cg * 8, lane, qid, ymax, ymin);
  }
}

template <int PHASE>
__global__ __launch_bounds__(64) void chain_kernel(
    const float4* __restrict__ pts4, const float* __restrict__ ft,
    const float4* __restrict__ q4, const int* __restrict__ nbr,
    const float* __restrict__ w0T, const float* __restrict__ w1T, const float* __restrict__ w2T,
    const float* __restrict__ sc1, const float* __restrict__ sh1,
    const float* __restrict__ sc2, const float* __restrict__ sh2,
    float* __restrict__ Psum, float* __restrict__ Psq,
    float* __restrict__ ymax, float* __restrict__ ymin)
{
  __shared__ float xt[C0 + 1][64];
  const int qid = blockIdx.x, b = qid >> 11, lane = threadIdx.x;
  const int rg = lane >> 3, cg = lane & 7;
  gather_x0(pts4, ft, q4, nbr, qid, b, lane, xt);
  float acc[8][8];
  conv_tile(acc, xt, w0T, 67, 64, cg * 8, rg);
  if (PHASE == 1) { stats_tile(acc, cg * 8, lane, qid, Psum, Psq); return; }
  bn_relu_store(acc, sc1, sh1, cg * 8, rg, xt);
  conv_tile(acc, xt, w1T, 64, 64, cg * 8, rg);
  if (PHASE == 2) { stats_tile(acc, cg * 8, lane, qid, Psum, Psq); return; }
  bn_relu_store(acc, sc2, sh2, cg * 8, rg, xt);
  conv_tile(acc, xt, w2T, 64, 128, cg * 8, rg);
  stats_tile(acc, cg * 8, lane, qid, Psum, Psq);
  maxmin_tile(acc, cg * 8, lane, qid, ymax, ymin);
  conv_tile(acc, xt, w2T, 64, 128, 64 + cg * 8, rg);
  stats_tile(acc, 64 + cg * 8, lane, qid, Psum, Psq);
  maxmin_tile(acc, 64 + cg * 8, lane, qid, ymax, ymin);
}

// ---------------------------------------------------------------- stats reduce
__global__ __launch_bounds__(256) void reduce_stats(
    const float* __restrict__ Psum, const float* __restrict__ Psq,
    const float* __restrict__ g, const float* __restrict__ beta,
    float* __restrict__ scale, float* __restrict__ shift)
{
  __shared__ float ls[256], lq[256];
  const int o = blockIdx.x, t = threadIdx.x;
  float s = 0.f, q = 0.f;
  for (int x = t; x < NB_CHAIN; x += 256) {
    s += Psum[(size_t)o * NB_CHAIN + x];
    q += Psq [(size_t)o * NB_CHAIN + x];
  }
  ls[t] = s; lq[t] = q;
  __syncthreads();
  for (int st = 128; st > 0; st >>= 1) {
    if (t < st) { ls[t] += ls[t + st]; lq[t] += lq[t + st]; }
    __syncthreads();
  }
  if (t == 0) {
    const float inv = 1.f / (float)NROW;
    float mu = ls[0] * inv;
    float var = lq[0] * inv - mu * mu;
    float scv = g[o] / sqrtf(var + 1e-5f);
    scale[o] = scv;
    shift[o] = beta[o] - mu * scv;
  }
}

// ---------------------------------------------------------------- final BN+maxpool
__global__ __launch_bounds__(256) void bn_final(
    const float* __restrict__ ymax, const float* __restrict__ ymin,
    const float* __restrict__ sc3, const float* __restrict__ sh3,
    float* __restrict__ out1)
{
  const int idx = blockIdx.x * 256 + threadIdx.x;
  const int ch = (idx >> 11) & 127;
  const int qid = ((idx >> 18) << 11) | (idx & 2047);
  const float sc = sc3[ch], sh = sh3[ch];
  const float v = (sc >= 0.f) ? ymax[(size_t)ch * NB_CHAIN + qid]
                              : ymin[(size_t)ch * NB_CHAIN + qid];
  out1[idx] = fmaxf(fmaf(v, sc, sh), 0.f);
}

// ---------------------------------------------------------------- launcher
extern "C" void kernel_launch(void* const* d_in, const int* in_sizes, int n_in,
                              void* d_out, int out_size, void* d_ws, size_t ws_size,
                              hipStream_t stream)
{
  const float* P  = (const float*)d_in[0];
  const float* F  = (const float*)d_in[1];
  const float* W0 = (const float*)d_in[2];
  const float* g0 = (const float*)d_in[3];
  const float* b0 = (const float*)d_in[4];
  const float* W1 = (const float*)d_in[5];
  const float* g1 = (const float*)d_in[6];
  const float* b1 = (const float*)d_in[7];
  const float* W2 = (const float*)d_in[8];
  const float* g2 = (const float*)d_in[9];
  const float* b2 = (const float*)d_in[10];

  float* out_q = (float*)d_out;           // (B,3,M)
  float* out_f = out_q + B * 3 * M;       // (B,128,M)

  char* w = (char*)d_ws;
  size_t off = 0;
  auto alloc = [&](size_t bytes) -> void* {
    off = (off + 255) & ~(size_t)255;
    void* p = w + off;
    off += bytes;
    return p;
  };
  float4* pts4 = (float4*)alloc((size_t)B * N * sizeof(float4));
  float*  ft   = (float*) alloc((size_t)B * N * 64 * 4);
  float*  w0T  = (float*) alloc(68 * 64 * 4);
  float*  w1T  = (float*) alloc(64 * 64 * 4);
  float*  w2T  = (float*) alloc(64 * 128 * 4);
  float4* q4   = (float4*)alloc((size_t)B * M * sizeof(float4));
  int*    nbr  = (int*)   alloc((size_t)B * M * K * 4);
  float*  Psum = (float*) alloc((size_t)128 * NB_CHAIN * 4);
  float*  Psq  = (float*) alloc((size_t)128 * NB_CHAIN * 4);
  float*  ymax = (float*) alloc((size_t)128 * NB_CHAIN * 4);
  float*  ymin = (float*) alloc((size_t)128 * NB_CHAIN * 4);
  float*  bnp  = (float*) alloc(6 * 128 * 4);
  float *sc1 = bnp, *sh1 = bnp + 128, *sc2 = bnp + 256, *sh2 = bnp + 384,
        *sc3 = bnp + 512, *sh3 = bnp + 640;
  const size_t ybytes = (size_t)NB_CHAIN * 64 * 64 * 4;   // 134 MB
  off = (off + 255) & ~(size_t)255;
  const bool have_y = (off + ybytes) <= ws_size;
  float* y = (float*)(w + off);
  (void)in_sizes; (void)n_in; (void)out_size;

  transpose_kernel<<<B * N / 256, 256, 0, stream>>>(P, F, pts4, ft);
  prep_weights<<<1, 256, 0, stream>>>(W0, W1, W2, w0T, w1T, w2T);
  fps_kernel<<<B, FPS_T, 0, stream>>>(P, q4, out_q);
  ballquery_kernel<<<B * M / 4, 256, 0, stream>>>(pts4, q4, nbr);

  if (have_y) {
    chain_p1<<<NB_CHAIN, 64, 0, stream>>>(pts4, ft, q4, nbr, w0T, Psum, Psq, y);
    reduce_stats<<<64, 256, 0, stream>>>(Psum, Psq, g0, b0, sc1, sh1);
    chain_p23<2><<<NB_CHAIN, 64, 0, stream>>>(w1T, sc1, sh1, Psum, Psq, y, ymax, ymin);
    reduce_stats<<<64, 256, 0, stream>>>(Psum, Psq, g1, b1, sc2, sh2);
    chain_p23<3><<<NB_CHAIN, 64, 0, stream>>>(w2T, sc2, sh2, Psum, Psq, y, ymax, ymin);
    reduce_stats<<<128, 256, 0, stream>>>(Psum, Psq, g2, b2, sc3, sh3);
  } else {
    chain_kernel<1><<<NB_CHAIN, 64, 0, stream>>>(pts4, ft, q4, nbr, w0T, w1T, w2T,
        sc1, sh1, sc2, sh2, Psum, Psq, ymax, ymin);
    reduce_stats<<<64, 256, 0, stream>>>(Psum, Psq, g0, b0, sc1, sh1);
    chain_kernel<2><<<NB_CHAIN, 64, 0, stream>>>(pts4, ft, q4, nbr, w0T, w1T, w2T,
        sc1, sh1, sc2, sh2, Psum, Psq, ymax, ymin);
    reduce_stats<<<64, 256, 0, stream>>>(Psum, Psq, g1, b1, sc2, sh2);
    chain_kernel<3><<<NB_CHAIN, 64, 0, stream>>>(pts4, ft, q4, nbr, w0T, w1T, w2T,
        sc1, sh1, sc2, sh2, Psum, Psq, ymax, ymin);
    reduce_stats<<<128, 256, 0, stream>>>(Psum, Psq, g2, b2, sc3, sh3);
  }
  bn_final<<<NB_CHAIN * 128 / 256, 256, 0, stream>>>(ymax, ymin, sc3, sh3, out_f);
}

// Round 11
// 2615.240 us; speedup vs baseline: 1.3066x; 1.3066x over previous
//
#include <hip/hip_runtime.h>
#include <math.h>

// PointNet++ SetAbstraction for MI355X.
// B=4 N=8192 M=2048 K=64 C_IN=64, dims 67->64->64->128, radius 0.2.
// Exactness-critical paths (FPS argmax + per-thread bbox pruning, ball-query
// radius test) use __f*_rn intrinsics; pruning relies on IEEE rounding
// monotonicity so skipped work is provably identity. No FMA in exact paths.

constexpr int B = 4, N = 8192, M = 2048, K = 64;
constexpr int C0 = 67;              // 3 + 64 input channels
constexpr int NB_CHAIN = B * M;     // one block per (b,m) = 8192
constexpr int NROW = B * M * K;     // 524288 rows through the MLP

#define DEVFN static __device__ __forceinline__

// DPP-shifted copy: invalid lanes get 0 (neutral for max of values >= 0).
template <int CTRL>
DEVFN float dpp_shift0(float x) {
  return __uint_as_float((unsigned)__builtin_amdgcn_update_dpp(
      0, (int)__float_as_uint(x), CTRL, 0xf, 0xf, true));
}
template <int CTRL>
DEVFN unsigned dpp_shift0u(unsigned x) {
  return (unsigned)__builtin_amdgcn_update_dpp(0, (int)x, CTRL, 0xf, 0xf, true);
}
// wave max broadcast via DPP chain + readlane (no LDS round-trips)
DEVFN float wave_max_bcast_f(float x) {
  x = fmaxf(x, dpp_shift0<0x111>(x));   // row_shr:1
  x = fmaxf(x, dpp_shift0<0x112>(x));   // row_shr:2
  x = fmaxf(x, dpp_shift0<0x114>(x));   // row_shr:4
  x = fmaxf(x, dpp_shift0<0x118>(x));   // row_shr:8
  x = fmaxf(x, dpp_shift0<0x142>(x));   // row_bcast:15
  x = fmaxf(x, dpp_shift0<0x143>(x));   // row_bcast:31 -> lane63
  return __uint_as_float(
      (unsigned)__builtin_amdgcn_readlane((int)__float_as_uint(x), 63));
}
DEVFN unsigned wave_max_bcast_u(unsigned x) {
  unsigned t;
  t = dpp_shift0u<0x111>(x); x = x > t ? x : t;
  t = dpp_shift0u<0x112>(x); x = x > t ? x : t;
  t = dpp_shift0u<0x114>(x); x = x > t ? x : t;
  t = dpp_shift0u<0x118>(x); x = x > t ? x : t;
  t = dpp_shift0u<0x142>(x); x = x > t ? x : t;
  t = dpp_shift0u<0x143>(x); x = x > t ? x : t;
  return (unsigned)__builtin_amdgcn_readlane((int)x, 63);
}

// ---------------------------------------------------------------- transpose
__global__ __launch_bounds__(256) void transpose_kernel(
    const float* __restrict__ P, const float* __restrict__ F,
    float4* __restrict__ pts4, float* __restrict__ ft)
{
  int g = blockIdx.x * 256 + threadIdx.x;        // 0 .. B*N-1
  int b = g >> 13, i = g & (N - 1);
  const float* Pb = P + (size_t)b * 3 * N;
  pts4[g] = make_float4(Pb[i], Pb[N + i], Pb[2 * N + i], 0.f);
  const float* Fb = F + (size_t)b * 64 * N;
  float* o = ft + (size_t)g * 64;
  #pragma unroll 8
  for (int c = 0; c < 64; ++c) o[c] = Fb[(size_t)c * N + i];
}

__global__ __launch_bounds__(256) void prep_weights(
    const float* __restrict__ W0, const float* __restrict__ W1,
    const float* __restrict__ W2,
    float* __restrict__ w0T, float* __restrict__ w1T, float* __restrict__ w2T)
{
  int t = threadIdx.x;
  for (int x = t; x < 67 * 64; x += 256) { int k = x >> 6, o = x & 63;  w0T[x] = W0[o * 67 + k]; }
  for (int x = t; x < 64 * 64; x += 256) { int k = x >> 6, o = x & 63;  w1T[x] = W1[o * 64 + k]; }
  for (int x = t; x < 64 * 128; x += 256){ int k = x >> 7, o = x & 127; w2T[x] = W2[o * 64 + k]; }
}

// ---------------------------------------------------------------- FPS
// Single-barrier brute-force skeleton (R7, 1852us) + per-thread pruning:
// points counting-sorted into 512 cells (8x8x8); thread t owns sorted block
// [16t,16t+16) with its bbox in 6 VGPRs. Per step: if dlow(bbox,c) >= bv
// (thread's running max-mind), every owned d >= mind (IEEE rn monotone) so
// minds AND the (bv,~oidx) candidate are unchanged -> skip, taken per wave
// via ballot. Tie rule exact: u64 (mind_bits<<32 | ~orig_idx) max.
// Wave reduce: DPP chains + readlane (no ds_bpermute on serial chain).
constexpr int FPS_T = 512;
constexpr int FPS_PT = 16;

__global__ __launch_bounds__(512) void fps_kernel(
    const float* __restrict__ P, float4* __restrict__ q4, float* __restrict__ out_q)
{
  __shared__ float4 sp4[N];                       // orig-indexed coords 128 KB
  __shared__ unsigned short ssort[N];             // sorted->orig map    16 KB
  __shared__ int hist[512];                       // histogram/cursor     2 KB
  __shared__ __align__(16) unsigned long long partial[2][8];
  __shared__ unsigned short swidx[M];             // winner orig idx      4 KB

  const int b = blockIdx.x, tid = threadIdx.x;
  const int wvid = tid >> 6, lane = tid & 63;
  const float* Pb = P + (size_t)b * 3 * N;

  hist[tid & 511] = 0;
  __syncthreads();

  // ---- load, write orig-indexed table, histogram cells
  int lcid[FPS_PT];
  #pragma unroll
  for (int j = 0; j < FPS_PT; ++j) {
    int i = tid + j * FPS_T;
    float x = Pb[i], y = Pb[N + i], z = Pb[2 * N + i];
    sp4[i] = make_float4(x, y, z, 0.f);
    int cxi = min((int)(x * 8.f), 7);
    int cyi = min((int)(y * 8.f), 7);
    int czi = min((int)(z * 8.f), 7);
    lcid[j] = (cxi << 6) | (cyi << 3) | czi;
    atomicAdd(&hist[lcid[j]], 1);
  }
  __syncthreads();
  if (tid == 0) {                                 // exclusive prefix (once)
    int acc = 0;
    for (int k = 0; k < 512; ++k) { int t = hist[k]; hist[k] = acc; acc += t; }
  }
  __syncthreads();
  #pragma unroll
  for (int j = 0; j < FPS_PT; ++j) {              // scatter sorted order
    int i = tid + j * FPS_T;
    int pos = atomicAdd(&hist[lcid[j]], 1);
    ssort[pos] = (unsigned short)i;
  }
  __syncthreads();

  // ---- adopt sorted block [16t,16t+16): coords+ids+minds in registers, bbox
  float px[FPS_PT], py[FPS_PT], pz[FPS_PT], mind[FPS_PT];
  unsigned noid[FPS_PT];                          // ~orig_idx
  float xlo = 1e30f, xhi = -1e30f, ylo = 1e30f, yhi = -1e30f, zlo = 1e30f, zhi = -1e30f;
  unsigned bno = 0;
  #pragma unroll
  for (int j = 0; j < FPS_PT; ++j) {
    int o = ssort[tid * FPS_PT + j];
    float4 p = sp4[o];
    px[j] = p.x; py[j] = p.y; pz[j] = p.z;
    noid[j] = ~(unsigned)o;
    mind[j] = 1e10f;
    xlo = fminf(xlo, p.x); xhi = fmaxf(xhi, p.x);
    ylo = fminf(ylo, p.y); yhi = fmaxf(yhi, p.y);
    zlo = fminf(zlo, p.z); zhi = fmaxf(zhi, p.z);
    bno = noid[j] > bno ? noid[j] : bno;          // stale candidate: min oidx
  }
  float bv = 1e10f;
  if (tid == 0) swidx[0] = 0;                     // centroid 0 = point 0
  float4 c0 = sp4[0];
  float cx = c0.x, cy = c0.y, cz = c0.z;

  for (int s = 1; s < M; ++s) {
    // prune check: register-only, ~14 VALU
    float ax = fmaxf(0.f, fmaxf(__fsub_rn(xlo, cx), __fsub_rn(cx, xhi)));
    float ay = fmaxf(0.f, fmaxf(__fsub_rn(ylo, cy), __fsub_rn(cy, yhi)));
    float az = fmaxf(0.f, fmaxf(__fsub_rn(zlo, cz), __fsub_rn(cz, zhi)));
    float dlow = __fadd_rn(__fadd_rn(__fmul_rn(ax, ax), __fmul_rn(ay, ay)), __fmul_rn(az, az));
    bool active = dlow < bv;                      // skip iff dlow >= bv
    if (__ballot(active) != 0ull) {               // whole wave recomputes
      float nbv = -1.f; unsigned nbn = 0u;
      #pragma unroll
      for (int j = 0; j < FPS_PT; ++j) {
        float dx = __fsub_rn(px[j], cx), dy = __fsub_rn(py[j], cy), dz = __fsub_rn(pz[j], cz);
        float d  = __fadd_rn(__fadd_rn(__fmul_rn(dx, dx), __fmul_rn(dy, dy)), __fmul_rn(dz, dz));
        float mm = fminf(mind[j], d);
        mind[j] = mm;
        bool t1 = mm > nbv;
        bool t2 = (mm == nbv) & (noid[j] > nbn);
        bool tk = t1 | t2;
        nbv = tk ? mm : nbv;
        nbn = tk ? noid[j] : nbn;
      }
      bv = nbv; bno = nbn;                        // inactive lanes: identical
    }
    // wave reduce: value max, then min orig idx among tied lanes
    float vmax = wave_max_bcast_f(bv);
    unsigned cand = (bv == vmax) ? bno : 0u;
    unsigned wor = wave_max_bcast_u(cand);
    const int buf = s & 1;
    if (lane == 0)
      partial[buf][wvid] = ((unsigned long long)__float_as_uint(vmax) << 32) | wor;
    __syncthreads();
    unsigned long long k0 = partial[buf][0];
    #pragma unroll
    for (int w = 1; w < 8; ++w) {
      unsigned long long o = partial[buf][w];
      k0 = (o > k0) ? o : k0;
    }
    const int worig = (int)((~(unsigned)(k0 & 0xFFFFFFFFull)) & (unsigned)(N - 1));
    const float4 c = sp4[worig];
    cx = c.x; cy = c.y; cz = c.z;
    if (tid == 0) swidx[s] = (unsigned short)worig;
  }
  __syncthreads();
  // bulk write-out of the selected centroids
  for (int s2 = tid; s2 < M; s2 += FPS_T) {
    const float4 c = sp4[swidx[s2]];
    q4[b * M + s2] = c;
    out_q[b * 3 * M + s2]         = c.x;
    out_q[b * 3 * M + M + s2]     = c.y;
    out_q[b * 3 * M + 2 * M + s2] = c.z;
  }
}

// ---------------------------------------------------------------- ball query
// One wave per centroid: first K in-radius indices ascending; pad with first.
__global__ __launch_bounds__(256) void ballquery_kernel(
    const float4* __restrict__ pts4, const float4* __restrict__ q4, int* __restrict__ nbr)
{
  __shared__ int slot[4][K];
  const int wv = threadIdx.x >> 6, lane = threadIdx.x & 63;
  const int qid = blockIdx.x * 4 + wv;
  const int b = qid >> 11;
  const float4 qc = q4[qid];
  const float4* pb = pts4 + (size_t)b * N;
  const float r2 = 0.04f;                 // float(0.2**2), strict <
  int count = 0;
  for (int c0 = 0; c0 < N; c0 += 64) {
    float4 p = pb[c0 + lane];
    float dx = __fsub_rn(p.x, qc.x), dy = __fsub_rn(p.y, qc.y), dz = __fsub_rn(p.z, qc.z);
    float d2 = __fadd_rn(__fadd_rn(__fmul_rn(dx, dx), __fmul_rn(dy, dy)), __fmul_rn(dz, dz));
    bool in = d2 < r2;
    unsigned long long mask = __ballot(in);
    int pos = count + (int)__popcll(mask & ((1ull << lane) - 1ull));
    if (in && pos < K) slot[wv][pos] = c0 + lane;
    count += (int)__popcll(mask);
    if (count >= K) break;
  }
  __syncthreads();
  int valid = count < K ? count : K;
  int v = 0;
  if (valid > 0) {
    int first = slot[wv][0];
    v = (lane < valid) ? slot[wv][lane] : first;
  }
  nbr[(size_t)qid * K + lane] = v;
}

// ---------------------------------------------------------------- MLP chain
DEVFN void conv_tile(float acc[8][8], const float (&xt)[C0 + 1][64],
                     const float* __restrict__ wT, int KK, int OC, int choff, int rg)
{
  #pragma unroll
  for (int i = 0; i < 8; ++i)
    #pragma unroll
    for (int j = 0; j < 8; ++j) acc[i][j] = 0.f;
  for (int k = 0; k < KK; ++k) {
    const float4 xa = *(const float4*)&xt[k][rg * 8];
    const float4 xb = *(const float4*)&xt[k][rg * 8 + 4];
    const float4 wa = *(const float4*)(wT + (size_t)k * OC + choff);
    const float4 wb = *(const float4*)(wT + (size_t)k * OC + choff + 4);
    const float xs[8] = {xa.x, xa.y, xa.z, xa.w, xb.x, xb.y, xb.z, xb.w};
    const float wv[8] = {wa.x, wa.y, wa.z, wa.w, wb.x, wb.y, wb.z, wb.w};
    #pragma unroll
    for (int i = 0; i < 8; ++i)
      #pragma unroll
      for (int j = 0; j < 8; ++j) acc[i][j] = fmaf(xs[i], wv[j], acc[i][j]);
  }
}

DEVFN void bn_relu_store(const float acc[8][8], const float* __restrict__ sc,
                         const float* __restrict__ sh, int choff, int rg,
                         float (&xt)[C0 + 1][64])
{
  float4 s0 = *(const float4*)(sc + choff), s1 = *(const float4*)(sc + choff + 4);
  float4 h0 = *(const float4*)(sh + choff), h1 = *(const float4*)(sh + choff + 4);
  const float scv[8] = {s0.x, s0.y, s0.z, s0.w, s1.x, s1.y, s1.z, s1.w};
  const float shv[8] = {h0.x, h0.y, h0.z, h0.w, h1.x, h1.y, h1.z, h1.w};
  __syncthreads();
  #pragma unroll
  for (int j = 0; j < 8; ++j) {
    float4 a, b;
    a.x = fmaxf(fmaf(acc[0][j], scv[j], shv[j]), 0.f);
    a.y = fmaxf(fmaf(acc[1][j], scv[j], shv[j]), 0.f);
    a.z = fmaxf(fmaf(acc[2][j], scv[j], shv[j]), 0.f);
    a.w = fmaxf(fmaf(acc[3][j], scv[j], shv[j]), 0.f);
    b.x = fmaxf(fmaf(acc[4][j], scv[j], shv[j]), 0.f);
    b.y = fmaxf(fmaf(acc[5][j], scv[j], shv[j]), 0.f);
    b.z = fmaxf(fmaf(acc[6][j], scv[j], shv[j]), 0.f);
    b.w = fmaxf(fmaf(acc[7][j], scv[j], shv[j]), 0.f);
    *(float4*)&xt[choff + j][rg * 8]     = a;
    *(float4*)&xt[choff + j][rg * 8 + 4] = b;
  }
  __syncthreads();
}

DEVFN void stats_tile(const float acc[8][8], int chbase, int lane, int qid,
                      float* __restrict__ Psum, float* __restrict__ Psq)
{
  #pragma unroll
  for (int j = 0; j < 8; ++j) {
    float s = 0.f, q = 0.f;
    #pragma unroll
    for (int i = 0; i < 8; ++i) { s += acc[i][j]; q = fmaf(acc[i][j], acc[i][j], q); }
    s += __shfl_xor(s, 8);  q += __shfl_xor(q, 8);
    s += __shfl_xor(s, 16); q += __shfl_xor(q, 16);
    s += __shfl_xor(s, 32); q += __shfl_xor(q, 32);
    if ((lane >> 3) == 0) {
      Psum[(size_t)(chbase + j) * NB_CHAIN + qid] = s;
      Psq [(size_t)(chbase + j) * NB_CHAIN + qid] = q;
    }
  }
}

DEVFN void maxmin_tile(const float acc[8][8], int chbase, int lane, int qid,
                       float* __restrict__ ymax, float* __restrict__ ymin)
{
  #pragma unroll
  for (int j = 0; j < 8; ++j) {
    float mx = acc[0][j], mn = acc[0][j];
    #pragma unroll
    for (int i = 1; i < 8; ++i) { mx = fmaxf(mx, acc[i][j]); mn = fminf(mn, acc[i][j]); }
    mx = fmaxf(mx, __shfl_xor(mx, 8));  mn = fminf(mn, __shfl_xor(mn, 8));
    mx = fmaxf(mx, __shfl_xor(mx, 16)); mn = fminf(mn, __shfl_xor(mn, 16));
    mx = fmaxf(mx, __shfl_xor(mx, 32)); mn = fminf(mn, __shfl_xor(mn, 32));
    if ((lane >> 3) == 0) {
      ymax[(size_t)(chbase + j) * NB_CHAIN + qid] = mx;
      ymin[(size_t)(chbase + j) * NB_CHAIN + qid] = mn;
    }
  }
}

DEVFN void gather_x0(const float4* __restrict__ pts4, const float* __restrict__ ft,
                     const float4* __restrict__ q4, const int* __restrict__ nbr,
                     int qid, int b, int lane, float (&xt)[C0 + 1][64])
{
  const int i = nbr[(size_t)qid * K + lane];
  const float4 qc = q4[qid];
  const float4 p = pts4[(size_t)b * N + i];
  xt[0][lane] = p.x - qc.x;
  xt[1][lane] = p.y - qc.y;
  xt[2][lane] = p.z - qc.z;
  const float4* fr = (const float4*)(ft + (size_t)(b * N + i) * 64);
  #pragma unroll
  for (int c = 0; c < 16; ++c) {
    float4 f = fr[c];
    xt[3 + 4 * c + 0][lane] = f.x;
    xt[3 + 4 * c + 1][lane] = f.y;
    xt[3 + 4 * c + 2][lane] = f.z;
    xt[3 + 4 * c + 3][lane] = f.w;
  }
  __syncthreads();
}

DEVFN void y_store(const float acc[8][8], float* __restrict__ y, int qid, int rg, int cg)
{
  float* base = y + (size_t)qid * 4096 + (size_t)(cg * 8) * 64 + rg * 8;
  #pragma unroll
  for (int j = 0; j < 8; ++j) {
    float4 a = make_float4(acc[0][j], acc[1][j], acc[2][j], acc[3][j]);
    float4 c = make_float4(acc[4][j], acc[5][j], acc[6][j], acc[7][j]);
    *(float4*)(base + (size_t)j * 64)     = a;
    *(float4*)(base + (size_t)j * 64 + 4) = c;
  }
}
DEVFN void y_load(float acc[8][8], const float* __restrict__ y, int qid, int rg, int cg)
{
  const float* base = y + (size_t)qid * 4096 + (size_t)(cg * 8) * 64 + rg * 8;
  #pragma unroll
  for (int j = 0; j < 8; ++j) {
    float4 a = *(const float4*)(base + (size_t)j * 64);
    float4 c = *(const float4*)(base + (size_t)j * 64 + 4);
    acc[0][j] = a.x; acc[1][j] = a.y; acc[2][j] = a.z; acc[3][j] = a.w;
    acc[4][j] = c.x; acc[5][j] = c.y; acc[6][j] = c.z; acc[7][j] = c.w;
  }
}

__global__ __launch_bounds__(64) void chain_p1(
    const float4* __restrict__ pts4, const float* __restrict__ ft,
    const float4* __restrict__ q4, const int* __restrict__ nbr,
    const float* __restrict__ w0T,
    float* __restrict__ Psum, float* __restrict__ Psq, float* __restrict__ y)
{
  __shared__ float xt[C0 + 1][64];
  const int qid = blockIdx.x, b = qid >> 11, lane = threadIdx.x;
  const int rg = lane >> 3, cg = lane & 7;
  gather_x0(pts4, ft, q4, nbr, qid, b, lane, xt);
  float acc[8][8];
  conv_tile(acc, xt, w0T, 67, 64, cg * 8, rg);
  stats_tile(acc, cg * 8, lane, qid, Psum, Psq);
  y_store(acc, y, qid, rg, cg);
}

template <int LAYER>
__global__ __launch_bounds__(64) void chain_p23(
    const float* __restrict__ wT, const float* __restrict__ sc,
    const float* __restrict__ sh,
    float* __restrict__ Psum, float* __restrict__ Psq,
    float* __restrict__ y, float* __restrict__ ymax, float* __restrict__ ymin)
{
  __shared__ float xt[C0 + 1][64];
  const int qid = blockIdx.x, lane = threadIdx.x;
  const int rg = lane >> 3, cg = lane & 7;
  float acc[8][8];
  y_load(acc, y, qid, rg, cg);
  bn_relu_store(acc, sc, sh, cg * 8, rg, xt);
  if (LAYER == 2) {
    conv_tile(acc, xt, wT, 64, 64, cg * 8, rg);
    stats_tile(acc, cg * 8, lane, qid, Psum, Psq);
    y_store(acc, y, qid, rg, cg);
  } else {
    conv_tile(acc, xt, wT, 64, 128, cg * 8, rg);
    stats_tile(acc, cg * 8, lane, qid, Psum, Psq);
    maxmin_tile(acc, cg * 8, lane, qid, ymax, ymin);
    conv_tile(acc, xt, wT, 64, 128, 64 + cg * 8, rg);
    stats_tile(acc, 64 + cg * 8, lane, qid, Psum, Psq);
    maxmin_tile(acc, 64 + cg * 8, lane, qid, ymax, ymin);
  }
}

template <int PHASE>
__global__ __launch_bounds__(64) void chain_kernel(
    const float4* __restrict__ pts4, const float* __restrict__ ft,
    const float4* __restrict__ q4, const int* __restrict__ nbr,
    const float* __restrict__ w0T, const float* __restrict__ w1T, const float* __restrict__ w2T,
    const float* __restrict__ sc1, const float* __restrict__ sh1,
    const float* __restrict__ sc2, const float* __restrict__ sh2,
    float* __restrict__ Psum, float* __restrict__ Psq,
    float* __restrict__ ymax, float* __restrict__ ymin)
{
  __shared__ float xt[C0 + 1][64];
  const int qid = blockIdx.x, b = qid >> 11, lane = threadIdx.x;
  const int rg = lane >> 3, cg = lane & 7;
  gather_x0(pts4, ft, q4, nbr, qid, b, lane, xt);
  float acc[8][8];
  conv_tile(acc, xt, w0T, 67, 64, cg * 8, rg);
  if (PHASE == 1) { stats_tile(acc, cg * 8, lane, qid, Psum, Psq); return; }
  bn_relu_store(acc, sc1, sh1, cg * 8, rg, xt);
  conv_tile(acc, xt, w1T, 64, 64, cg * 8, rg);
  if (PHASE == 2) { stats_tile(acc, cg * 8, lane, qid, Psum, Psq); return; }
  bn_relu_store(acc, sc2, sh2, cg * 8, rg, xt);
  conv_tile(acc, xt, w2T, 64, 128, cg * 8, rg);
  stats_tile(acc, cg * 8, lane, qid, Psum, Psq);
  maxmin_tile(acc, cg * 8, lane, qid, ymax, ymin);
  conv_tile(acc, xt, w2T, 64, 128, 64 + cg * 8, rg);
  stats_tile(acc, 64 + cg * 8, lane, qid, Psum, Psq);
  maxmin_tile(acc, 64 + cg * 8, lane, qid, ymax, ymin);
}

// ---------------------------------------------------------------- stats reduce
__global__ __launch_bounds__(256) void reduce_stats(
    const float* __restrict__ Psum, const float* __restrict__ Psq,
    const float* __restrict__ g, const float* __restrict__ beta,
    float* __restrict__ scale, float* __restrict__ shift)
{
  __shared__ float ls[256], lq[256];
  const int o = blockIdx.x, t = threadIdx.x;
  float s = 0.f, q = 0.f;
  for (int x = t; x < NB_CHAIN; x += 256) {
    s += Psum[(size_t)o * NB_CHAIN + x];
    q += Psq [(size_t)o * NB_CHAIN + x];
  }
  ls[t] = s; lq[t] = q;
  __syncthreads();
  for (int st = 128; st > 0; st >>= 1) {
    if (t < st) { ls[t] += ls[t + st]; lq[t] += lq[t + st]; }
    __syncthreads();
  }
  if (t == 0) {
    const float inv = 1.f / (float)NROW;
    float mu = ls[0] * inv;
    float var = lq[0] * inv - mu * mu;
    float scv = g[o] / sqrtf(var + 1e-5f);
    scale[o] = scv;
    shift[o] = beta[o] - mu * scv;
  }
}

// ---------------------------------------------------------------- final BN+maxpool
__global__ __launch_bounds__(256) void bn_final(
    const float* __restrict__ ymax, const float* __restrict__ ymin,
    const float* __restrict__ sc3, const float* __restrict__ sh3,
    float* __restrict__ out1)
{
  const int idx = blockIdx.x * 256 + threadIdx.x;
  const int ch = (idx >> 11) & 127;
  const int qid = ((idx >> 18) << 11) | (idx & 2047);
  const float sc = sc3[ch], sh = sh3[ch];
  const float v = (sc >= 0.f) ? ymax[(size_t)ch * NB_CHAIN + qid]
                              : ymin[(size_t)ch * NB_CHAIN + qid];
  out1[idx] = fmaxf(fmaf(v, sc, sh), 0.f);
}

// ---------------------------------------------------------------- launcher
extern "C" void kernel_launch(void* const* d_in, const int* in_sizes, int n_in,
                              void* d_out, int out_size, void* d_ws, size_t ws_size,
                              hipStream_t stream)
{
  const float* P  = (const float*)d_in[0];
  const float* F  = (const float*)d_in[1];
  const float* W0 = (const float*)d_in[2];
  const float* g0 = (const float*)d_in[3];
  const float* b0 = (const float*)d_in[4];
  const float* W1 = (const float*)d_in[5];
  const float* g1 = (const float*)d_in[6];
  const float* b1 = (const float*)d_in[7];
  const float* W2 = (const float*)d_in[8];
  const float* g2 = (const float*)d_in[9];
  const float* b2 = (const float*)d_in[10];

  float* out_q = (float*)d_out;           // (B,3,M)
  float* out_f = out_q + B * 3 * M;       // (B,128,M)

  char* w = (char*)d_ws;
  size_t off = 0;
  auto alloc = [&](size_t bytes) -> void* {
    off = (off + 255) & ~(size_t)255;
    void* p = w + off;
    off += bytes;
    return p;
  };
  float4* pts4 = (float4*)alloc((size_t)B * N * sizeof(float4));
  float*  ft   = (float*) alloc((size_t)B * N * 64 * 4);
  float*  w0T  = (float*) alloc(68 * 64 * 4);
  float*  w1T  = (float*) alloc(64 * 64 * 4);
  float*  w2T  = (float*) alloc(64 * 128 * 4);
  float4* q4   = (float4*)alloc((size_t)B * M * sizeof(float4));
  int*    nbr  = (int*)   alloc((size_t)B * M * K * 4);
  float*  Psum = (float*) alloc((size_t)128 * NB_CHAIN * 4);
  float*  Psq  = (float*) alloc((size_t)128 * NB_CHAIN * 4);
  float*  ymax = (float*) alloc((size_t)128 * NB_CHAIN * 4);
  float*  ymin = (float*) alloc((size_t)128 * NB_CHAIN * 4);
  float*  bnp  = (float*) alloc(6 * 128 * 4);
  float *sc1 = bnp, *sh1 = bnp + 128, *sc2 = bnp + 256, *sh2 = bnp + 384,
        *sc3 = bnp + 512, *sh3 = bnp + 640;
  const size_t ybytes = (size_t)NB_CHAIN * 64 * 64 * 4;   // 134 MB
  off = (off + 255) & ~(size_t)255;
  const bool have_y = (off + ybytes) <= ws_size;
  float* y = (float*)(w + off);
  (void)in_sizes; (void)n_in; (void)out_size;

  transpose_kernel<<<B * N / 256, 256, 0, stream>>>(P, F, pts4, ft);
  prep_weights<<<1, 256, 0, stream>>>(W0, W1, W2, w0T, w1T, w2T);
  fps_kernel<<<B, FPS_T, 0, stream>>>(P, q4, out_q);
  ballquery_kernel<<<B * M / 4, 256, 0, stream>>>(pts4, q4, nbr);

  if (have_y) {
    chain_p1<<<NB_CHAIN, 64, 0, stream>>>(pts4, ft, q4, nbr, w0T, Psum, Psq, y);
    reduce_stats<<<64, 256, 0, stream>>>(Psum, Psq, g0, b0, sc1, sh1);
    chain_p23<2><<<NB_CHAIN, 64, 0, stream>>>(w1T, sc1, sh1, Psum, Psq, y, ymax, ymin);
    reduce_stats<<<64, 256, 0, stream>>>(Psum, Psq, g1, b1, sc2, sh2);
    chain_p23<3><<<NB_CHAIN, 64, 0, stream>>>(w2T, sc2, sh2, Psum, Psq, y, ymax, ymin);
    reduce_stats<<<128, 256, 0, stream>>>(Psum, Psq, g2, b2, sc3, sh3);
  } else {
    chain_kernel<1><<<NB_CHAIN, 64, 0, stream>>>(pts4, ft, q4, nbr, w0T, w1T, w2T,
        sc1, sh1, sc2, sh2, Psum, Psq, ymax, ymin);
    reduce_stats<<<64, 256, 0, stream>>>(Psum, Psq, g0, b0, sc1, sh1);
    chain_kernel<2><<<NB_CHAIN, 64, 0, stream>>>(pts4, ft, q4, nbr, w0T, w1T, w2T,
        sc1, sh1, sc2, sh2, Psum, Psq, ymax, ymin);
    reduce_stats<<<64, 256, 0, stream>>>(Psum, Psq, g1, b1, sc2, sh2);
    chain_kernel<3><<<NB_CHAIN, 64, 0, stream>>>(pts4, ft, q4, nbr, w0T, w1T, w2T,
        sc1, sh1, sc2, sh2, Psum, Psq, ymax, ymin);
    reduce_stats<<<128, 256, 0, stream>>>(Psum, Psq, g2, b2, sc3, sh3);
  }
  bn_final<<<NB_CHAIN * 128 / 256, 256, 0, stream>>>(ymax, ymin, sc3, sh3, out_f);
}

// Round 12
// 2307.209 us; speedup vs baseline: 1.4810x; 1.1335x over previous
//
#include <hip/hip_runtime.h>
#include <math.h>

// PointNet++ SetAbstraction for MI355X.
// B=4 N=8192 M=2048 K=64 C_IN=64, dims 67->64->64->128, radius 0.2.
// Exactness-critical paths (FPS argmax, ball-query radius test) use
// __f*_rn intrinsics to bit-match plain IEEE mul/add (no FMA contraction).

constexpr int B = 4, N = 8192, M = 2048, K = 64;
constexpr int C0 = 67;              // 3 + 64 input channels
constexpr int NB_CHAIN = B * M;     // one block per (b,m) = 8192
constexpr int NROW = B * M * K;     // 524288 rows through the MLP

#define DEVFN static __device__ __forceinline__

// DPP-shifted copy: invalid lanes get 0 (safe under max of values >= 0).
template <int CTRL>
DEVFN float dpp_shift0(float x) {
  return __uint_as_float((unsigned)__builtin_amdgcn_update_dpp(
      0, (int)__float_as_uint(x), CTRL, 0xf, 0xf, true));
}

// ---------------------------------------------------------------- transpose
__global__ __launch_bounds__(256) void transpose_kernel(
    const float* __restrict__ P, const float* __restrict__ F,
    float4* __restrict__ pts4, float* __restrict__ ft)
{
  int g = blockIdx.x * 256 + threadIdx.x;        // 0 .. B*N-1
  int b = g >> 13, i = g & (N - 1);
  const float* Pb = P + (size_t)b * 3 * N;
  pts4[g] = make_float4(Pb[i], Pb[N + i], Pb[2 * N + i], 0.f);
  const float* Fb = F + (size_t)b * 64 * N;
  float* o = ft + (size_t)g * 64;
  #pragma unroll 8
  for (int c = 0; c < 64; ++c) o[c] = Fb[(size_t)c * N + i];
}

__global__ __launch_bounds__(256) void prep_weights(
    const float* __restrict__ W0, const float* __restrict__ W1,
    const float* __restrict__ W2,
    float* __restrict__ w0T, float* __restrict__ w1T, float* __restrict__ w2T)
{
  int t = threadIdx.x;
  for (int x = t; x < 67 * 64; x += 256) { int k = x >> 6, o = x & 63;  w0T[x] = W0[o * 67 + k]; }
  for (int x = t; x < 64 * 64; x += 256) { int k = x >> 6, o = x & 63;  w1T[x] = W1[o * 64 + k]; }
  for (int x = t; x < 64 * 128; x += 256){ int k = x >> 7, o = x & 127; w2T[x] = W2[o * 64 + k]; }
}

// ---------------------------------------------------------------- FPS
// One block per batch; 512 threads (2 waves/SIMD). Thread t owns
// CONTIGUOUS points [16t,16t+16) -> lane order == index order, so
// value-tie -> lowest lane wins. Wave argmax: DPP max chain (pure VALU)
// -> lane 63; BOTH cross-lane fetches are v_readlane (SALU, wave-uniform
// index) instead of ds_bpermute -- no LDS round-trips on the serial
// chain. Cross-wave: u64 key (value_bits<<32 | ~idx) via one barrier +
// double-buffered partials. No global ops in loop; bulk write at end.
constexpr int FPS_T = 512;
constexpr int FPS_PT = N / FPS_T;   // 16

__global__ __launch_bounds__(512) void fps_kernel(
    const float* __restrict__ P, float4* __restrict__ q4, float* __restrict__ out_q)
{
  __shared__ float4 sp4[N];                             // 128 KB point table
  __shared__ __align__(16) unsigned long long partial[2][8];
  __shared__ unsigned short swidx[M];                   // 4 KB winner idx
  const int b = blockIdx.x, tid = threadIdx.x;
  const float* Pb = P + (size_t)b * 3 * N;

  float px[FPS_PT], py[FPS_PT], pz[FPS_PT], mind[FPS_PT];
  #pragma unroll
  for (int j = 0; j < FPS_PT; ++j) {
    int i = tid * FPS_PT + j;                           // contiguous block
    px[j] = Pb[i]; py[j] = Pb[N + i]; pz[j] = Pb[2 * N + i];
    sp4[i] = make_float4(px[j], py[j], pz[j], 0.f);
    mind[j] = 1e10f;
  }
  if (tid == 0) swidx[0] = 0;                           // centroid 0 = point 0
  __syncthreads();

  float cx = Pb[0], cy = Pb[N], cz = Pb[2 * N];

  for (int s = 1; s < M; ++s) {
    // phase A: exact min-update + per-thread argmax (value, lowest idx)
    float bv = -1.f; int bi = 0;
    #pragma unroll
    for (int j = 0; j < FPS_PT; ++j) {
      float dx = __fsub_rn(px[j], cx), dy = __fsub_rn(py[j], cy), dz = __fsub_rn(pz[j], cz);
      float d  = __fadd_rn(__fadd_rn(__fmul_rn(dx, dx), __fmul_rn(dy, dy)), __fmul_rn(dz, dz));
      float mm = fminf(mind[j], d);
      mind[j] = mm;
      bool tk = mm > bv;                 // strict > keeps lowest index (j ascending)
      bv = tk ? mm : bv;
      bi = tk ? tid * FPS_PT + j : bi;
    }
    // wave argmax via DPP (all values >= 0; 0-fill is neutral for max)
    float r = bv;
    r = fmaxf(r, dpp_shift0<0x111>(r));   // row_shr:1
    r = fmaxf(r, dpp_shift0<0x112>(r));   // row_shr:2
    r = fmaxf(r, dpp_shift0<0x114>(r));   // row_shr:4
    r = fmaxf(r, dpp_shift0<0x118>(r));   // row_shr:8  -> lane15 of each row
    r = fmaxf(r, dpp_shift0<0x142>(r));   // row_bcast:15
    r = fmaxf(r, dpp_shift0<0x143>(r));   // row_bcast:31 -> lane 63 global
    float wv = __uint_as_float(
        (unsigned)__builtin_amdgcn_readlane((int)__float_as_uint(r), 63));
    // lowest tied lane holds the smallest candidate index (SALU path)
    unsigned long long tied = __ballot(bv == wv);
    int wl = __ffsll(tied) - 1;
    int wi = __builtin_amdgcn_readlane(bi, wl);
    unsigned long long key =
        ((unsigned long long)__float_as_uint(wv) << 32) | (unsigned int)(~wi);
    const int buf = s & 1;
    if ((tid & 63) == 0) partial[buf][tid >> 6] = key;
    __syncthreads();
    // all threads reduce the 8 wave partials redundantly
    unsigned long long k0 = partial[buf][0];
    #pragma unroll
    for (int w = 1; w < 8; ++w) {
      unsigned long long o = partial[buf][w];
      k0 = (o > k0) ? o : k0;
    }
    const int widx = (int)(~(unsigned int)(k0 & 0xFFFFFFFFull)) & (N - 1);
    const float4 c = sp4[widx];
    cx = c.x; cy = c.y; cz = c.z;
    if (tid == 0) swidx[s] = (unsigned short)widx;
  }
  __syncthreads();
  // bulk write-out of the selected centroids
  for (int s = tid; s < M; s += FPS_T) {
    const float4 c = sp4[swidx[s]];
    q4[b * M + s] = c;
    out_q[b * 3 * M + s]         = c.x;
    out_q[b * 3 * M + M + s]     = c.y;
    out_q[b * 3 * M + 2 * M + s] = c.z;
  }
}

// ---------------------------------------------------------------- ball query
// One wave per centroid: first K in-radius indices ascending; pad with first.
__global__ __launch_bounds__(256) void ballquery_kernel(
    const float4* __restrict__ pts4, const float4* __restrict__ q4, int* __restrict__ nbr)
{
  __shared__ int slot[4][K];
  const int wv = threadIdx.x >> 6, lane = threadIdx.x & 63;
  const int qid = blockIdx.x * 4 + wv;
  const int b = qid >> 11;
  const float4 qc = q4[qid];
  const float4* pb = pts4 + (size_t)b * N;
  const float r2 = 0.04f;                 // float(0.2**2), strict <
  int count = 0;
  for (int c0 = 0; c0 < N; c0 += 64) {
    float4 p = pb[c0 + lane];
    float dx = __fsub_rn(p.x, qc.x), dy = __fsub_rn(p.y, qc.y), dz = __fsub_rn(p.z, qc.z);
    float d2 = __fadd_rn(__fadd_rn(__fmul_rn(dx, dx), __fmul_rn(dy, dy)), __fmul_rn(dz, dz));
    bool in = d2 < r2;
    unsigned long long mask = __ballot(in);
    int pos = count + (int)__popcll(mask & ((1ull << lane) - 1ull));
    if (in && pos < K) slot[wv][pos] = c0 + lane;
    count += (int)__popcll(mask);
    if (count >= K) break;
  }
  __syncthreads();
  int valid = count < K ? count : K;
  int v = 0;
  if (valid > 0) {
    int first = slot[wv][0];
    v = (lane < valid) ? slot[wv][lane] : first;
  }
  nbr[(size_t)qid * K + lane] = v;
}

// ---------------------------------------------------------------- MLP chain
DEVFN void conv_tile(float acc[8][8], const float (&xt)[C0 + 1][64],
                     const float* __restrict__ wT, int KK, int OC, int choff, int rg)
{
  #pragma unroll
  for (int i = 0; i < 8; ++i)
    #pragma unroll
    for (int j = 0; j < 8; ++j) acc[i][j] = 0.f;
  for (int k = 0; k < KK; ++k) {
    const float4 xa = *(const float4*)&xt[k][rg * 8];
    const float4 xb = *(const float4*)&xt[k][rg * 8 + 4];
    const float4 wa = *(const float4*)(wT + (size_t)k * OC + choff);
    const float4 wb = *(const float4*)(wT + (size_t)k * OC + choff + 4);
    const float xs[8] = {xa.x, xa.y, xa.z, xa.w, xb.x, xb.y, xb.z, xb.w};
    const float wv[8] = {wa.x, wa.y, wa.z, wa.w, wb.x, wb.y, wb.z, wb.w};
    #pragma unroll
    for (int i = 0; i < 8; ++i)
      #pragma unroll
      for (int j = 0; j < 8; ++j) acc[i][j] = fmaf(xs[i], wv[j], acc[i][j]);
  }
}

DEVFN void bn_relu_store(const float acc[8][8], const float* __restrict__ sc,
                         const float* __restrict__ sh, int choff, int rg,
                         float (&xt)[C0 + 1][64])
{
  float4 s0 = *(const float4*)(sc + choff), s1 = *(const float4*)(sc + choff + 4);
  float4 h0 = *(const float4*)(sh + choff), h1 = *(const float4*)(sh + choff + 4);
  const float scv[8] = {s0.x, s0.y, s0.z, s0.w, s1.x, s1.y, s1.z, s1.w};
  const float shv[8] = {h0.x, h0.y, h0.z, h0.w, h1.x, h1.y, h1.z, h1.w};
  __syncthreads();
  #pragma unroll
  for (int j = 0; j < 8; ++j) {
    float4 a, b;
    a.x = fmaxf(fmaf(acc[0][j], scv[j], shv[j]), 0.f);
    a.y = fmaxf(fmaf(acc[1][j], scv[j], shv[j]), 0.f);
    a.z = fmaxf(fmaf(acc[2][j], scv[j], shv[j]), 0.f);
    a.w = fmaxf(fmaf(acc[3][j], scv[j], shv[j]), 0.f);
    b.x = fmaxf(fmaf(acc[4][j], scv[j], shv[j]), 0.f);
    b.y = fmaxf(fmaf(acc[5][j], scv[j], shv[j]), 0.f);
    b.z = fmaxf(fmaf(acc[6][j], scv[j], shv[j]), 0.f);
    b.w = fmaxf(fmaf(acc[7][j], scv[j], shv[j]), 0.f);
    *(float4*)&xt[choff + j][rg * 8]     = a;
    *(float4*)&xt[choff + j][rg * 8 + 4] = b;
  }
  __syncthreads();
}

DEVFN void stats_tile(const float acc[8][8], int chbase, int lane, int qid,
                      float* __restrict__ Psum, float* __restrict__ Psq)
{
  #pragma unroll
  for (int j = 0; j < 8; ++j) {
    float s = 0.f, q = 0.f;
    #pragma unroll
    for (int i = 0; i < 8; ++i) { s += acc[i][j]; q = fmaf(acc[i][j], acc[i][j], q); }
    s += __shfl_xor(s, 8);  q += __shfl_xor(q, 8);
    s += __shfl_xor(s, 16); q += __shfl_xor(q, 16);
    s += __shfl_xor(s, 32); q += __shfl_xor(q, 32);
    if ((lane >> 3) == 0) {
      Psum[(size_t)(chbase + j) * NB_CHAIN + qid] = s;
      Psq [(size_t)(chbase + j) * NB_CHAIN + qid] = q;
    }
  }
}

DEVFN void maxmin_tile(const float acc[8][8], int chbase, int lane, int qid,
                       float* __restrict__ ymax, float* __restrict__ ymin)
{
  #pragma unroll
  for (int j = 0; j < 8; ++j) {
    float mx = acc[0][j], mn = acc[0][j];
    #pragma unroll
    for (int i = 1; i < 8; ++i) { mx = fmaxf(mx, acc[i][j]); mn = fminf(mn, acc[i][j]); }
    mx = fmaxf(mx, __shfl_xor(mx, 8));  mn = fminf(mn, __shfl_xor(mn, 8));
    mx = fmaxf(mx, __shfl_xor(mx, 16)); mn = fminf(mn, __shfl_xor(mn, 16));
    mx = fmaxf(mx, __shfl_xor(mx, 32)); mn = fminf(mn, __shfl_xor(mn, 32));
    if ((lane >> 3) == 0) {
      ymax[(size_t)(chbase + j) * NB_CHAIN + qid] = mx;
      ymin[(size_t)(chbase + j) * NB_CHAIN + qid] = mn;
    }
  }
}

DEVFN void gather_x0(const float4* __restrict__ pts4, const float* __restrict__ ft,
                     const float4* __restrict__ q4, const int* __restrict__ nbr,
                     int qid, int b, int lane, float (&xt)[C0 + 1][64])
{
  const int i = nbr[(size_t)qid * K + lane];
  const float4 qc = q4[qid];
  const float4 p = pts4[(size_t)b * N + i];
  xt[0][lane] = p.x - qc.x;
  xt[1][lane] = p.y - qc.y;
  xt[2][lane] = p.z - qc.z;
  const float4* fr = (const float4*)(ft + (size_t)(b * N + i) * 64);
  #pragma unroll
  for (int c = 0; c < 16; ++c) {
    float4 f = fr[c];
    xt[3 + 4 * c + 0][lane] = f.x;
    xt[3 + 4 * c + 1][lane] = f.y;
    xt[3 + 4 * c + 2][lane] = f.z;
    xt[3 + 4 * c + 3][lane] = f.w;
  }
  __syncthreads();
}

DEVFN void y_store(const float acc[8][8], float* __restrict__ y, int qid, int rg, int cg)
{
  float* base = y + (size_t)qid * 4096 + (size_t)(cg * 8) * 64 + rg * 8;
  #pragma unroll
  for (int j = 0; j < 8; ++j) {
    float4 a = make_float4(acc[0][j], acc[1][j], acc[2][j], acc[3][j]);
    float4 c = make_float4(acc[4][j], acc[5][j], acc[6][j], acc[7][j]);
    *(float4*)(base + (size_t)j * 64)     = a;
    *(float4*)(base + (size_t)j * 64 + 4) = c;
  }
}
DEVFN void y_load(float acc[8][8], const float* __restrict__ y, int qid, int rg, int cg)
{
  const float* base = y + (size_t)qid * 4096 + (size_t)(cg * 8) * 64 + rg * 8;
  #pragma unroll
  for (int j = 0; j < 8; ++j) {
    float4 a = *(const float4*)(base + (size_t)j * 64);
    float4 c = *(const float4*)(base + (size_t)j * 64 + 4);
    acc[0][j] = a.x; acc[1][j] = a.y; acc[2][j] = a.z; acc[3][j] = a.w;
    acc[4][j] = c.x; acc[5][j] = c.y; acc[6][j] = c.z; acc[7][j] = c.w;
  }
}

__global__ __launch_bounds__(64) void chain_p1(
    const float4* __restrict__ pts4, const float* __restrict__ ft,
    const float4* __restrict__ q4, const int* __restrict__ nbr,
    const float* __restrict__ w0T,
    float* __restrict__ Psum, float* __restrict__ Psq, float* __restrict__ y)
{
  __shared__ float xt[C0 + 1][64];
  const int qid = blockIdx.x, b = qid >> 11, lane = threadIdx.x;
  const int rg = lane >> 3, cg = lane & 7;
  gather_x0(pts4, ft, q4, nbr, qid, b, lane, xt);
  float acc[8][8];
  conv_tile(acc, xt, w0T, 67, 64, cg * 8, rg);
  stats_tile(acc, cg * 8, lane, qid, Psum, Psq);
  y_store(acc, y, qid, rg, cg);
}

template <int LAYER>
__global__ __launch_bounds__(64) void chain_p23(
    const float* __restrict__ wT, const float* __restrict__ sc,
    const float* __restrict__ sh,
    float* __restrict__ Psum, float* __restrict__ Psq,
    float* __restrict__ y, float* __restrict__ ymax, float* __restrict__ ymin)
{
  __shared__ float xt[C0 + 1][64];
  const int qid = blockIdx.x, lane = threadIdx.x;
  const int rg = lane >> 3, cg = lane & 7;
  float acc[8][8];
  y_load(acc, y, qid, rg, cg);
  bn_relu_store(acc, sc, sh, cg * 8, rg, xt);
  if (LAYER == 2) {
    conv_tile(acc, xt, wT, 64, 64, cg * 8, rg);
    stats_tile(acc, cg * 8, lane, qid, Psum, Psq);
    y_store(acc, y, qid, rg, cg);
  } else {
    conv_tile(acc, xt, wT, 64, 128, cg * 8, rg);
    stats_tile(acc, cg * 8, lane, qid, Psum, Psq);
    maxmin_tile(acc, cg * 8, lane, qid, ymax, ymin);
    conv_tile(acc, xt, wT, 64, 128, 64 + cg * 8, rg);
    stats_tile(acc, 64 + cg * 8, lane, qid, Psum, Psq);
    maxmin_tile(acc, 64 + cg * 8, lane, qid, ymax, ymin);
  }
}

template <int PHASE>
__global__ __launch_bounds__(64) void chain_kernel(
    const float4* __restrict__ pts4, const float* __restrict__ ft,
    const float4* __restrict__ q4, const int* __restrict__ nbr,
    const float* __restrict__ w0T, const float* __restrict__ w1T, const float* __restrict__ w2T,
    const float* __restrict__ sc1, const float* __restrict__ sh1,
    const float* __restrict__ sc2, const float* __restrict__ sh2,
    float* __restrict__ Psum, float* __restrict__ Psq,
    float* __restrict__ ymax, float* __restrict__ ymin)
{
  __shared__ float xt[C0 + 1][64];
  const int qid = blockIdx.x, b = qid >> 11, lane = threadIdx.x;
  const int rg = lane >> 3, cg = lane & 7;
  gather_x0(pts4, ft, q4, nbr, qid, b, lane, xt);
  float acc[8][8];
  conv_tile(acc, xt, w0T, 67, 64, cg * 8, rg);
  if (PHASE == 1) { stats_tile(acc, cg * 8, lane, qid, Psum, Psq); return; }
  bn_relu_store(acc, sc1, sh1, cg * 8, rg, xt);
  conv_tile(acc, xt, w1T, 64, 64, cg * 8, rg);
  if (PHASE == 2) { stats_tile(acc, cg * 8, lane, qid, Psum, Psq); return; }
  bn_relu_store(acc, sc2, sh2, cg * 8, rg, xt);
  conv_tile(acc, xt, w2T, 64, 128, cg * 8, rg);
  stats_tile(acc, cg * 8, lane, qid, Psum, Psq);
  maxmin_tile(acc, cg * 8, lane, qid, ymax, ymin);
  conv_tile(acc, xt, w2T, 64, 128, 64 + cg * 8, rg);
  stats_tile(acc, 64 + cg * 8, lane, qid, Psum, Psq);
  maxmin_tile(acc, 64 + cg * 8, lane, qid, ymax, ymin);
}

// ---------------------------------------------------------------- stats reduce
__global__ __launch_bounds__(256) void reduce_stats(
    const float* __restrict__ Psum, const float* __restrict__ Psq,
    const float* __restrict__ g, const float* __restrict__ beta,
    float* __restrict__ scale, float* __restrict__ shift)
{
  __shared__ float ls[256], lq[256];
  const int o = blockIdx.x, t = threadIdx.x;
  float s = 0.f, q = 0.f;
  for (int x = t; x < NB_CHAIN; x += 256) {
    s += Psum[(size_t)o * NB_CHAIN + x];
    q += Psq [(size_t)o * NB_CHAIN + x];
  }
  ls[t] = s; lq[t] = q;
  __syncthreads();
  for (int st = 128; st > 0; st >>= 1) {
    if (t < st) { ls[t] += ls[t + st]; lq[t] += lq[t + st]; }
    __syncthreads();
  }
  if (t == 0) {
    const float inv = 1.f / (float)NROW;
    float mu = ls[0] * inv;
    float var = lq[0] * inv - mu * mu;
    float scv = g[o] / sqrtf(var + 1e-5f);
    scale[o] = scv;
    shift[o] = beta[o] - mu * scv;
  }
}

// ---------------------------------------------------------------- final BN+maxpool
__global__ __launch_bounds__(256) void bn_final(
    const float* __restrict__ ymax, const float* __restrict__ ymin,
    const float* __restrict__ sc3, const float* __restrict__ sh3,
    float* __restrict__ out1)
{
  const int idx = blockIdx.x * 256 + threadIdx.x;
  const int ch = (idx >> 11) & 127;
  const int qid = ((idx >> 18) << 11) | (idx & 2047);
  const float sc = sc3[ch], sh = sh3[ch];
  const float v = (sc >= 0.f) ? ymax[(size_t)ch * NB_CHAIN + qid]
                              : ymin[(size_t)ch * NB_CHAIN + qid];
  out1[idx] = fmaxf(fmaf(v, sc, sh), 0.f);
}

// ---------------------------------------------------------------- launcher
extern "C" void kernel_launch(void* const* d_in, const int* in_sizes, int n_in,
                              void* d_out, int out_size, void* d_ws, size_t ws_size,
                              hipStream_t stream)
{
  const float* P  = (const float*)d_in[0];
  const float* F  = (const float*)d_in[1];
  const float* W0 = (const float*)d_in[2];
  const float* g0 = (const float*)d_in[3];
  const float* b0 = (const float*)d_in[4];
  const float* W1 = (const float*)d_in[5];
  const float* g1 = (const float*)d_in[6];
  const float* b1 = (const float*)d_in[7];
  const float* W2 = (const float*)d_in[8];
  const float* g2 = (const float*)d_in[9];
  const float* b2 = (const float*)d_in[10];

  float* out_q = (float*)d_out;           // (B,3,M)
  float* out_f = out_q + B * 3 * M;       // (B,128,M)

  char* w = (char*)d_ws;
  size_t off = 0;
  auto alloc = [&](size_t bytes) -> void* {
    off = (off + 255) & ~(size_t)255;
    void* p = w + off;
    off += bytes;
    return p;
  };
  float4* pts4 = (float4*)alloc((size_t)B * N * sizeof(float4));
  float*  ft   = (float*) alloc((size_t)B * N * 64 * 4);
  float*  w0T  = (float*) alloc(68 * 64 * 4);
  float*  w1T  = (float*) alloc(64 * 64 * 4);
  float*  w2T  = (float*) alloc(64 * 128 * 4);
  float4* q4   = (float4*)alloc((size_t)B * M * sizeof(float4));
  int*    nbr  = (int*)   alloc((size_t)B * M * K * 4);
  float*  Psum = (float*) alloc((size_t)128 * NB_CHAIN * 4);
  float*  Psq  = (float*) alloc((size_t)128 * NB_CHAIN * 4);
  float*  ymax = (float*) alloc((size_t)128 * NB_CHAIN * 4);
  float*  ymin = (float*) alloc((size_t)128 * NB_CHAIN * 4);
  float*  bnp  = (float*) alloc(6 * 128 * 4);
  float *sc1 = bnp, *sh1 = bnp + 128, *sc2 = bnp + 256, *sh2 = bnp + 384,
        *sc3 = bnp + 512, *sh3 = bnp + 640;
  const size_t ybytes = (size_t)NB_CHAIN * 64 * 64 * 4;   // 134 MB
  off = (off + 255) & ~(size_t)255;
  const bool have_y = (off + ybytes) <= ws_size;
  float* y = (float*)(w + off);
  (void)in_sizes; (void)n_in; (void)out_size;

  transpose_kernel<<<B * N / 256, 256, 0, stream>>>(P, F, pts4, ft);
  prep_weights<<<1, 256, 0, stream>>>(W0, W1, W2, w0T, w1T, w2T);
  fps_kernel<<<B, FPS_T, 0, stream>>>(P, q4, out_q);
  ballquery_kernel<<<B * M / 4, 256, 0, stream>>>(pts4, q4, nbr);

  if (have_y) {
    chain_p1<<<NB_CHAIN, 64, 0, stream>>>(pts4, ft, q4, nbr, w0T, Psum, Psq, y);
    reduce_stats<<<64, 256, 0, stream>>>(Psum, Psq, g0, b0, sc1, sh1);
    chain_p23<2><<<NB_CHAIN, 64, 0, stream>>>(w1T, sc1, sh1, Psum, Psq, y, ymax, ymin);
    reduce_stats<<<64, 256, 0, stream>>>(Psum, Psq, g1, b1, sc2, sh2);
    chain_p23<3><<<NB_CHAIN, 64, 0, stream>>>(w2T, sc2, sh2, Psum, Psq, y, ymax, ymin);
    reduce_stats<<<128, 256, 0, stream>>>(Psum, Psq, g2, b2, sc3, sh3);
  } else {
    chain_kernel<1><<<NB_CHAIN, 64, 0, stream>>>(pts4, ft, q4, nbr, w0T, w1T, w2T,
        sc1, sh1, sc2, sh2, Psum, Psq, ymax, ymin);
    reduce_stats<<<64, 256, 0, stream>>>(Psum, Psq, g0, b0, sc1, sh1);
    chain_kernel<2><<<NB_CHAIN, 64, 0, stream>>>(pts4, ft, q4, nbr, w0T, w1T, w2T,
        sc1, sh1, sc2, sh2, Psum, Psq, ymax, ymin);
    reduce_stats<<<64, 256, 0, stream>>>(Psum, Psq, g1, b1, sc2, sh2);
    chain_kernel<3><<<NB_CHAIN, 64, 0, stream>>>(pts4, ft, q4, nbr, w0T, w1T, w2T,
        sc1, sh1, sc2, sh2, Psum, Psq, ymax, ymin);
    reduce_stats<<<128, 256, 0, stream>>>(Psum, Psq, g2, b2, sc3, sh3);
  }
  bn_final<<<NB_CHAIN * 128 / 256, 256, 0, stream>>>(ymax, ymin, sc3, sh3, out_f);
}

// Round 13
// 2294.994 us; speedup vs baseline: 1.4889x; 1.0053x over previous
//
#include <hip/hip_runtime.h>
#include <math.h>

// PointNet++ SetAbstraction for MI355X.
// B=4 N=8192 M=2048 K=64 C_IN=64, dims 67->64->64->128, radius 0.2.
// Exactness-critical paths (FPS argmax, ball-query radius test) use
// __f*_rn intrinsics to bit-match plain IEEE mul/add (no FMA contraction).
// fused_pre: blocks 0-3 run FPS (4 CUs); blocks 4-67 transpose; block 68
// preps weights -- independent work overlaps FPS instead of serializing.

constexpr int B = 4, N = 8192, M = 2048, K = 64;
constexpr int C0 = 67;              // 3 + 64 input channels
constexpr int NB_CHAIN = B * M;     // one block per (b,m) = 8192
constexpr int NROW = B * M * K;     // 524288 rows through the MLP

#define DEVFN static __device__ __forceinline__

// DPP-shifted copy: invalid lanes get 0 (safe under max of values >= 0).
template <int CTRL>
DEVFN float dpp_shift0(float x) {
  return __uint_as_float((unsigned)__builtin_amdgcn_update_dpp(
      0, (int)__float_as_uint(x), CTRL, 0xf, 0xf, true));
}

// ---------------------------------------------------------------- fused pre
// FPS (R12 form, local optimum): one block per batch; 512 threads
// (2 waves/SIMD). Thread t owns CONTIGUOUS points [16t,16t+16) -> lane
// order == index order, value-tie -> lowest lane wins. Wave argmax: DPP
// max chain (pure VALU) -> lane 63; cross-lane fetches are v_readlane
// (SALU) -- no LDS round-trips on the serial chain. Cross-wave: u64 key
// (value_bits<<32 | ~idx), one barrier + double-buffered partials.
constexpr int FPS_T = 512;
constexpr int FPS_PT = N / FPS_T;   // 16

__global__ __launch_bounds__(512) void fused_pre(
    const float* __restrict__ P, const float* __restrict__ F,
    float4* __restrict__ pts4, float* __restrict__ ft,
    float4* __restrict__ q4, float* __restrict__ out_q,
    const float* __restrict__ W0, const float* __restrict__ W1,
    const float* __restrict__ W2,
    float* __restrict__ w0T, float* __restrict__ w1T, float* __restrict__ w2T)
{
  __shared__ float4 sp4[N];                             // 128 KB point table
  __shared__ __align__(16) unsigned long long partial[2][8];
  __shared__ unsigned short swidx[M];                   // 4 KB winner idx
  const int blk = blockIdx.x, tid = threadIdx.x;

  if (blk >= 4) {
    if (blk < 68) {                                     // ---- transpose part
      int g = (blk - 4) * 512 + tid;                    // 0 .. B*N-1
      int b = g >> 13, i = g & (N - 1);
      const float* Pb = P + (size_t)b * 3 * N;
      pts4[g] = make_float4(Pb[i], Pb[N + i], Pb[2 * N + i], 0.f);
      const float* Fb = F + (size_t)b * 64 * N;
      float* o = ft + (size_t)g * 64;
      #pragma unroll 8
      for (int c = 0; c < 64; ++c) o[c] = Fb[(size_t)c * N + i];
    } else {                                            // ---- weight prep
      for (int x = tid; x < 67 * 64; x += 512) { int k = x >> 6, o = x & 63;  w0T[x] = W0[o * 67 + k]; }
      for (int x = tid; x < 64 * 64; x += 512) { int k = x >> 6, o = x & 63;  w1T[x] = W1[o * 64 + k]; }
      for (int x = tid; x < 64 * 128; x += 512){ int k = x >> 7, o = x & 127; w2T[x] = W2[o * 64 + k]; }
    }
    return;
  }

  // ---- FPS part (blocks 0..3)
  const int b = blk;
  const float* Pb = P + (size_t)b * 3 * N;

  float px[FPS_PT], py[FPS_PT], pz[FPS_PT], mind[FPS_PT];
  #pragma unroll
  for (int j = 0; j < FPS_PT; ++j) {
    int i = tid * FPS_PT + j;                           // contiguous block
    px[j] = Pb[i]; py[j] = Pb[N + i]; pz[j] = Pb[2 * N + i];
    sp4[i] = make_float4(px[j], py[j], pz[j], 0.f);
    mind[j] = 1e10f;
  }
  if (tid == 0) swidx[0] = 0;                           // centroid 0 = point 0
  __syncthreads();

  float cx = Pb[0], cy = Pb[N], cz = Pb[2 * N];

  for (int s = 1; s < M; ++s) {
    // phase A: exact min-update + per-thread argmax (value, lowest idx)
    float bv = -1.f; int bi = 0;
    #pragma unroll
    for (int j = 0; j < FPS_PT; ++j) {
      float dx = __fsub_rn(px[j], cx), dy = __fsub_rn(py[j], cy), dz = __fsub_rn(pz[j], cz);
      float d  = __fadd_rn(__fadd_rn(__fmul_rn(dx, dx), __fmul_rn(dy, dy)), __fmul_rn(dz, dz));
      float mm = fminf(mind[j], d);
      mind[j] = mm;
      bool tk = mm > bv;                 // strict > keeps lowest index (j ascending)
      bv = tk ? mm : bv;
      bi = tk ? tid * FPS_PT + j : bi;
    }
    // wave argmax via DPP (all values >= 0; 0-fill is neutral for max)
    float r = bv;
    r = fmaxf(r, dpp_shift0<0x111>(r));   // row_shr:1
    r = fmaxf(r, dpp_shift0<0x112>(r));   // row_shr:2
    r = fmaxf(r, dpp_shift0<0x114>(r));   // row_shr:4
    r = fmaxf(r, dpp_shift0<0x118>(r));   // row_shr:8  -> lane15 of each row
    r = fmaxf(r, dpp_shift0<0x142>(r));   // row_bcast:15
    r = fmaxf(r, dpp_shift0<0x143>(r));   // row_bcast:31 -> lane 63 global
    float wv = __uint_as_float(
        (unsigned)__builtin_amdgcn_readlane((int)__float_as_uint(r), 63));
    // lowest tied lane holds the smallest candidate index (SALU path)
    unsigned long long tied = __ballot(bv == wv);
    int wl = __ffsll(tied) - 1;
    int wi = __builtin_amdgcn_readlane(bi, wl);
    unsigned long long key =
        ((unsigned long long)__float_as_uint(wv) << 32) | (unsigned int)(~wi);
    const int buf = s & 1;
    if ((tid & 63) == 0) partial[buf][tid >> 6] = key;
    __syncthreads();
    // all threads reduce the 8 wave partials redundantly
    unsigned long long k0 = partial[buf][0];
    #pragma unroll
    for (int w = 1; w < 8; ++w) {
      unsigned long long o = partial[buf][w];
      k0 = (o > k0) ? o : k0;
    }
    const int widx = (int)(~(unsigned int)(k0 & 0xFFFFFFFFull)) & (N - 1);
    const float4 c = sp4[widx];
    cx = c.x; cy = c.y; cz = c.z;
    if (tid == 0) swidx[s] = (unsigned short)widx;
  }
  __syncthreads();
  // bulk write-out of the selected centroids
  for (int s = tid; s < M; s += FPS_T) {
    const float4 c = sp4[swidx[s]];
    q4[b * M + s] = c;
    out_q[b * 3 * M + s]         = c.x;
    out_q[b * 3 * M + M + s]     = c.y;
    out_q[b * 3 * M + 2 * M + s] = c.z;
  }
}

// ---------------------------------------------------------------- ball query
// One wave per centroid: first K in-radius indices ascending; pad with first.
__global__ __launch_bounds__(256) void ballquery_kernel(
    const float4* __restrict__ pts4, const float4* __restrict__ q4, int* __restrict__ nbr)
{
  __shared__ int slot[4][K];
  const int wv = threadIdx.x >> 6, lane = threadIdx.x & 63;
  const int qid = blockIdx.x * 4 + wv;
  const int b = qid >> 11;
  const float4 qc = q4[qid];
  const float4* pb = pts4 + (size_t)b * N;
  const float r2 = 0.04f;                 // float(0.2**2), strict <
  int count = 0;
  for (int c0 = 0; c0 < N; c0 += 64) {
    float4 p = pb[c0 + lane];
    float dx = __fsub_rn(p.x, qc.x), dy = __fsub_rn(p.y, qc.y), dz = __fsub_rn(p.z, qc.z);
    float d2 = __fadd_rn(__fadd_rn(__fmul_rn(dx, dx), __fmul_rn(dy, dy)), __fmul_rn(dz, dz));
    bool in = d2 < r2;
    unsigned long long mask = __ballot(in);
    int pos = count + (int)__popcll(mask & ((1ull << lane) - 1ull));
    if (in && pos < K) slot[wv][pos] = c0 + lane;
    count += (int)__popcll(mask);
    if (count >= K) break;
  }
  __syncthreads();
  int valid = count < K ? count : K;
  int v = 0;
  if (valid > 0) {
    int first = slot[wv][0];
    v = (lane < valid) ? slot[wv][lane] : first;
  }
  nbr[(size_t)qid * K + lane] = v;
}

// ---------------------------------------------------------------- MLP chain
DEVFN void conv_tile(float acc[8][8], const float (&xt)[C0 + 1][64],
                     const float* __restrict__ wT, int KK, int OC, int choff, int rg)
{
  #pragma unroll
  for (int i = 0; i < 8; ++i)
    #pragma unroll
    for (int j = 0; j < 8; ++j) acc[i][j] = 0.f;
  for (int k = 0; k < KK; ++k) {
    const float4 xa = *(const float4*)&xt[k][rg * 8];
    const float4 xb = *(const float4*)&xt[k][rg * 8 + 4];
    const float4 wa = *(const float4*)(wT + (size_t)k * OC + choff);
    const float4 wb = *(const float4*)(wT + (size_t)k * OC + choff + 4);
    const float xs[8] = {xa.x, xa.y, xa.z, xa.w, xb.x, xb.y, xb.z, xb.w};
    const float wv[8] = {wa.x, wa.y, wa.z, wa.w, wb.x, wb.y, wb.z, wb.w};
    #pragma unroll
    for (int i = 0; i < 8; ++i)
      #pragma unroll
      for (int j = 0; j < 8; ++j) acc[i][j] = fmaf(xs[i], wv[j], acc[i][j]);
  }
}

DEVFN void bn_relu_store(const float acc[8][8], const float* __restrict__ sc,
                         const float* __restrict__ sh, int choff, int rg,
                         float (&xt)[C0 + 1][64])
{
  float4 s0 = *(const float4*)(sc + choff), s1 = *(const float4*)(sc + choff + 4);
  float4 h0 = *(const float4*)(sh + choff), h1 = *(const float4*)(sh + choff + 4);
  const float scv[8] = {s0.x, s0.y, s0.z, s0.w, s1.x, s1.y, s1.z, s1.w};
  const float shv[8] = {h0.x, h0.y, h0.z, h0.w, h1.x, h1.y, h1.z, h1.w};
  __syncthreads();
  #pragma unroll
  for (int j = 0; j < 8; ++j) {
    float4 a, b;
    a.x = fmaxf(fmaf(acc[0][j], scv[j], shv[j]), 0.f);
    a.y = fmaxf(fmaf(acc[1][j], scv[j], shv[j]), 0.f);
    a.z = fmaxf(fmaf(acc[2][j], scv[j], shv[j]), 0.f);
    a.w = fmaxf(fmaf(acc[3][j], scv[j], shv[j]), 0.f);
    b.x = fmaxf(fmaf(acc[4][j], scv[j], shv[j]), 0.f);
    b.y = fmaxf(fmaf(acc[5][j], scv[j], shv[j]), 0.f);
    b.z = fmaxf(fmaf(acc[6][j], scv[j], shv[j]), 0.f);
    b.w = fmaxf(fmaf(acc[7][j], scv[j], shv[j]), 0.f);
    *(float4*)&xt[choff + j][rg * 8]     = a;
    *(float4*)&xt[choff + j][rg * 8 + 4] = b;
  }
  __syncthreads();
}

DEVFN void stats_tile(const float acc[8][8], int chbase, int lane, int qid,
                      float* __restrict__ Psum, float* __restrict__ Psq)
{
  #pragma unroll
  for (int j = 0; j < 8; ++j) {
    float s = 0.f, q = 0.f;
    #pragma unroll
    for (int i = 0; i < 8; ++i) { s += acc[i][j]; q = fmaf(acc[i][j], acc[i][j], q); }
    s += __shfl_xor(s, 8);  q += __shfl_xor(q, 8);
    s += __shfl_xor(s, 16); q += __shfl_xor(q, 16);
    s += __shfl_xor(s, 32); q += __shfl_xor(q, 32);
    if ((lane >> 3) == 0) {
      Psum[(size_t)(chbase + j) * NB_CHAIN + qid] = s;
      Psq [(size_t)(chbase + j) * NB_CHAIN + qid] = q;
    }
  }
}

DEVFN void maxmin_tile(const float acc[8][8], int chbase, int lane, int qid,
                       float* __restrict__ ymax, float* __restrict__ ymin)
{
  #pragma unroll
  for (int j = 0; j < 8; ++j) {
    float mx = acc[0][j], mn = acc[0][j];
    #pragma unroll
    for (int i = 1; i < 8; ++i) { mx = fmaxf(mx, acc[i][j]); mn = fminf(mn, acc[i][j]); }
    mx = fmaxf(mx, __shfl_xor(mx, 8));  mn = fminf(mn, __shfl_xor(mn, 8));
    mx = fmaxf(mx, __shfl_xor(mx, 16)); mn = fminf(mn, __shfl_xor(mn, 16));
    mx = fmaxf(mx, __shfl_xor(mx, 32)); mn = fminf(mn, __shfl_xor(mn, 32));
    if ((lane >> 3) == 0) {
      ymax[(size_t)(chbase + j) * NB_CHAIN + qid] = mx;
      ymin[(size_t)(chbase + j) * NB_CHAIN + qid] = mn;
    }
  }
}

DEVFN void gather_x0(const float4* __restrict__ pts4, const float* __restrict__ ft,
                     const float4* __restrict__ q4, const int* __restrict__ nbr,
                     int qid, int b, int lane, float (&xt)[C0 + 1][64])
{
  const int i = nbr[(size_t)qid * K + lane];
  const float4 qc = q4[qid];
  const float4 p = pts4[(size_t)b * N + i];
  xt[0][lane] = p.x - qc.x;
  xt[1][lane] = p.y - qc.y;
  xt[2][lane] = p.z - qc.z;
  const float4* fr = (const float4*)(ft + (size_t)(b * N + i) * 64);
  #pragma unroll
  for (int c = 0; c < 16; ++c) {
    float4 f = fr[c];
    xt[3 + 4 * c + 0][lane] = f.x;
    xt[3 + 4 * c + 1][lane] = f.y;
    xt[3 + 4 * c + 2][lane] = f.z;
    xt[3 + 4 * c + 3][lane] = f.w;
  }
  __syncthreads();
}

DEVFN void y_store(const float acc[8][8], float* __restrict__ y, int qid, int rg, int cg)
{
  float* base = y + (size_t)qid * 4096 + (size_t)(cg * 8) * 64 + rg * 8;
  #pragma unroll
  for (int j = 0; j < 8; ++j) {
    float4 a = make_float4(acc[0][j], acc[1][j], acc[2][j], acc[3][j]);
    float4 c = make_float4(acc[4][j], acc[5][j], acc[6][j], acc[7][j]);
    *(float4*)(base + (size_t)j * 64)     = a;
    *(float4*)(base + (size_t)j * 64 + 4) = c;
  }
}
DEVFN void y_load(float acc[8][8], const float* __restrict__ y, int qid, int rg, int cg)
{
  const float* base = y + (size_t)qid * 4096 + (size_t)(cg * 8) * 64 + rg * 8;
  #pragma unroll
  for (int j = 0; j < 8; ++j) {
    float4 a = *(const float4*)(base + (size_t)j * 64);
    float4 c = *(const float4*)(base + (size_t)j * 64 + 4);
    acc[0][j] = a.x; acc[1][j] = a.y; acc[2][j] = a.z; acc[3][j] = a.w;
    acc[4][j] = c.x; acc[5][j] = c.y; acc[6][j] = c.z; acc[7][j] = c.w;
  }
}

__global__ __launch_bounds__(64) void chain_p1(
    const float4* __restrict__ pts4, const float* __restrict__ ft,
    const float4* __restrict__ q4, const int* __restrict__ nbr,
    const float* __restrict__ w0T,
    float* __restrict__ Psum, float* __restrict__ Psq, float* __restrict__ y)
{
  __shared__ float xt[C0 + 1][64];
  const int qid = blockIdx.x, b = qid >> 11, lane = threadIdx.x;
  const int rg = lane >> 3, cg = lane & 7;
  gather_x0(pts4, ft, q4, nbr, qid, b, lane, xt);
  float acc[8][8];
  conv_tile(acc, xt, w0T, 67, 64, cg * 8, rg);
  stats_tile(acc, cg * 8, lane, qid, Psum, Psq);
  y_store(acc, y, qid, rg, cg);
}

template <int LAYER>
__global__ __launch_bounds__(64) void chain_p23(
    const float* __restrict__ wT, const float* __restrict__ sc,
    const float* __restrict__ sh,
    float* __restrict__ Psum, float* __restrict__ Psq,
    float* __restrict__ y, float* __restrict__ ymax, float* __restrict__ ymin)
{
  __shared__ float xt[C0 + 1][64];
  const int qid = blockIdx.x, lane = threadIdx.x;
  const int rg = lane >> 3, cg = lane & 7;
  float acc[8][8];
  y_load(acc, y, qid, rg, cg);
  bn_relu_store(acc, sc, sh, cg * 8, rg, xt);
  if (LAYER == 2) {
    conv_tile(acc, xt, wT, 64, 64, cg * 8, rg);
    stats_tile(acc, cg * 8, lane, qid, Psum, Psq);
    y_store(acc, y, qid, rg, cg);
  } else {
    conv_tile(acc, xt, wT, 64, 128, cg * 8, rg);
    stats_tile(acc, cg * 8, lane, qid, Psum, Psq);
    maxmin_tile(acc, cg * 8, lane, qid, ymax, ymin);
    conv_tile(acc, xt, wT, 64, 128, 64 + cg * 8, rg);
    stats_tile(acc, 64 + cg * 8, lane, qid, Psum, Psq);
    maxmin_tile(acc, 64 + cg * 8, lane, qid, ymax, ymin);
  }
}

template <int PHASE>
__global__ __launch_bounds__(64) void chain_kernel(
    const float4* __restrict__ pts4, const float* __restrict__ ft,
    const float4* __restrict__ q4, const int* __restrict__ nbr,
    const float* __restrict__ w0T, const float* __restrict__ w1T, const float* __restrict__ w2T,
    const float* __restrict__ sc1, const float* __restrict__ sh1,
    const float* __restrict__ sc2, const float* __restrict__ sh2,
    float* __restrict__ Psum, float* __restrict__ Psq,
    float* __restrict__ ymax, float* __restrict__ ymin)
{
  __shared__ float xt[C0 + 1][64];
  const int qid = blockIdx.x, b = qid >> 11, lane = threadIdx.x;
  const int rg = lane >> 3, cg = lane & 7;
  gather_x0(pts4, ft, q4, nbr, qid, b, lane, xt);
  float acc[8][8];
  conv_tile(acc, xt, w0T, 67, 64, cg * 8, rg);
  if (PHASE == 1) { stats_tile(acc, cg * 8, lane, qid, Psum, Psq); return; }
  bn_relu_store(acc, sc1, sh1, cg * 8, rg, xt);
  conv_tile(acc, xt, w1T, 64, 64, cg * 8, rg);
  if (PHASE == 2) { stats_tile(acc, cg * 8, lane, qid, Psum, Psq); return; }
  bn_relu_store(acc, sc2, sh2, cg * 8, rg, xt);
  conv_tile(acc, xt, w2T, 64, 128, cg * 8, rg);
  stats_tile(acc, cg * 8, lane, qid, Psum, Psq);
  maxmin_tile(acc, cg * 8, lane, qid, ymax, ymin);
  conv_tile(acc, xt, w2T, 64, 128, 64 + cg * 8, rg);
  stats_tile(acc, 64 + cg * 8, lane, qid, Psum, Psq);
  maxmin_tile(acc, 64 + cg * 8, lane, qid, ymax, ymin);
}

// ---------------------------------------------------------------- stats reduce
__global__ __launch_bounds__(256) void reduce_stats(
    const float* __restrict__ Psum, const float* __restrict__ Psq,
    const float* __restrict__ g, const float* __restrict__ beta,
    float* __restrict__ scale, float* __restrict__ shift)
{
  __shared__ float ls[256], lq[256];
  const int o = blockIdx.x, t = threadIdx.x;
  float s = 0.f, q = 0.f;
  for (int x = t; x < NB_CHAIN; x += 256) {
    s += Psum[(size_t)o * NB_CHAIN + x];
    q += Psq [(size_t)o * NB_CHAIN + x];
  }
  ls[t] = s; lq[t] = q;
  __syncthreads();
  for (int st = 128; st > 0; st >>= 1) {
    if (t < st) { ls[t] += ls[t + st]; lq[t] += lq[t + st]; }
    __syncthreads();
  }
  if (t == 0) {
    const float inv = 1.f / (float)NROW;
    float mu = ls[0] * inv;
    float var = lq[0] * inv - mu * mu;
    float scv = g[o] / sqrtf(var + 1e-5f);
    scale[o] = scv;
    shift[o] = beta[o] - mu * scv;
  }
}

// ---------------------------------------------------------------- final BN+maxpool
__global__ __launch_bounds__(256) void bn_final(
    const float* __restrict__ ymax, const float* __restrict__ ymin,
    const float* __restrict__ sc3, const float* __restrict__ sh3,
    float* __restrict__ out1)
{
  const int idx = blockIdx.x * 256 + threadIdx.x;
  const int ch = (idx >> 11) & 127;
  const int qid = ((idx >> 18) << 11) | (idx & 2047);
  const float sc = sc3[ch], sh = sh3[ch];
  const float v = (sc >= 0.f) ? ymax[(size_t)ch * NB_CHAIN + qid]
                              : ymin[(size_t)ch * NB_CHAIN + qid];
  out1[idx] = fmaxf(fmaf(v, sc, sh), 0.f);
}

// ---------------------------------------------------------------- launcher
extern "C" void kernel_launch(void* const* d_in, const int* in_sizes, int n_in,
                              void* d_out, int out_size, void* d_ws, size_t ws_size,
                              hipStream_t stream)
{
  const float* P  = (const float*)d_in[0];
  const float* F  = (const float*)d_in[1];
  const float* W0 = (const float*)d_in[2];
  const float* g0 = (const float*)d_in[3];
  const float* b0 = (const float*)d_in[4];
  const float* W1 = (const float*)d_in[5];
  const float* g1 = (const float*)d_in[6];
  const float* b1 = (const float*)d_in[7];
  const float* W2 = (const float*)d_in[8];
  const float* g2 = (const float*)d_in[9];
  const float* b2 = (const float*)d_in[10];

  float* out_q = (float*)d_out;           // (B,3,M)
  float* out_f = out_q + B * 3 * M;       // (B,128,M)

  char* w = (char*)d_ws;
  size_t off = 0;
  auto alloc = [&](size_t bytes) -> void* {
    off = (off + 255) & ~(size_t)255;
    void* p = w + off;
    off += bytes;
    return p;
  };
  float4* pts4 = (float4*)alloc((size_t)B * N * sizeof(float4));
  float*  ft   = (float*) alloc((size_t)B * N * 64 * 4);
  float*  w0T  = (float*) alloc(68 * 64 * 4);
  float*  w1T  = (float*) alloc(64 * 64 * 4);
  float*  w2T  = (float*) alloc(64 * 128 * 4);
  float4* q4   = (float4*)alloc((size_t)B * M * sizeof(float4));
  int*    nbr  = (int*)   alloc((size_t)B * M * K * 4);
  float*  Psum = (float*) alloc((size_t)128 * NB_CHAIN * 4);
  float*  Psq  = (float*) alloc((size_t)128 * NB_CHAIN * 4);
  float*  ymax = (float*) alloc((size_t)128 * NB_CHAIN * 4);
  float*  ymin = (float*) alloc((size_t)128 * NB_CHAIN * 4);
  float*  bnp  = (float*) alloc(6 * 128 * 4);
  float *sc1 = bnp, *sh1 = bnp + 128, *sc2 = bnp + 256, *sh2 = bnp + 384,
        *sc3 = bnp + 512, *sh3 = bnp + 640;
  const size_t ybytes = (size_t)NB_CHAIN * 64 * 64 * 4;   // 134 MB
  off = (off + 255) & ~(size_t)255;
  const bool have_y = (off + ybytes) <= ws_size;
  float* y = (float*)(w + off);
  (void)in_sizes; (void)n_in; (void)out_size;

  // blocks 0-3: FPS; 4-67: transpose; 68: weight prep (overlapped)
  fused_pre<<<69, FPS_T, 0, stream>>>(P, F, pts4, ft, q4, out_q,
                                      W0, W1, W2, w0T, w1T, w2T);
  ballquery_kernel<<<B * M / 4, 256, 0, stream>>>(pts4, q4, nbr);

  if (have_y) {
    chain_p1<<<NB_CHAIN, 64, 0, stream>>>(pts4, ft, q4, nbr, w0T, Psum, Psq, y);
    reduce_stats<<<64, 256, 0, stream>>>(Psum, Psq, g0, b0, sc1, sh1);
    chain_p23<2><<<NB_CHAIN, 64, 0, stream>>>(w1T, sc1, sh1, Psum, Psq, y, ymax, ymin);
    reduce_stats<<<64, 256, 0, stream>>>(Psum, Psq, g1, b1, sc2, sh2);
    chain_p23<3><<<NB_CHAIN, 64, 0, stream>>>(w2T, sc2, sh2, Psum, Psq, y, ymax, ymin);
    reduce_stats<<<128, 256, 0, stream>>>(Psum, Psq, g2, b2, sc3, sh3);
  } else {
    chain_kernel<1><<<NB_CHAIN, 64, 0, stream>>>(pts4, ft, q4, nbr, w0T, w1T, w2T,
        sc1, sh1, sc2, sh2, Psum, Psq, ymax, ymin);
    reduce_stats<<<64, 256, 0, stream>>>(Psum, Psq, g0, b0, sc1, sh1);
    chain_kernel<2><<<NB_CHAIN, 64, 0, stream>>>(pts4, ft, q4, nbr, w0T, w1T, w2T,
        sc1, sh1, sc2, sh2, Psum, Psq, ymax, ymin);
    reduce_stats<<<64, 256, 0, stream>>>(Psum, Psq, g1, b1, sc2, sh2);
    chain_kernel<3><<<NB_CHAIN, 64, 0, stream>>>(pts4, ft, q4, nbr, w0T, w1T, w2T,
        sc1, sh1, sc2, sh2, Psum, Psq, ymax, ymin);
    reduce_stats<<<128, 256, 0, stream>>>(Psum, Psq, g2, b2, sc3, sh3);
  }
  bn_final<<<NB_CHAIN * 128 / 256, 256, 0, stream>>>(ymax, ymin, sc3, sh3, out_f);
}